// Round 13
// baseline (694.877 us; speedup 1.0000x reference)
//
#include <hip/hip_runtime.h>
#include <hip/hip_bf16.h>

typedef __attribute__((ext_vector_type(8))) short bf16x8;
typedef __attribute__((ext_vector_type(4))) float f32x4;

static inline int cdiv(int a, int b) { return (a + b - 1) / b; }

__device__ __forceinline__ ushort f2bf(float f) {
    unsigned u = __float_as_uint(f);
    unsigned r = (u + 0x7FFFu + ((u >> 16) & 1u)) >> 16;
    return (ushort)r;
}
__device__ __forceinline__ unsigned pack2bf(float lo, float hi) {
    unsigned r;
    asm("v_cvt_pk_bf16_f32 %0, %1, %2" : "=v"(r) : "v"(lo), "v"(hi));
    return r;
}
__device__ __forceinline__ float bf2f(ushort u) {
    return __uint_as_float((unsigned)u << 16);
}
__device__ __forceinline__ int iclamp(int v, int lo, int hi) {
    return v < lo ? lo : (v > hi ? hi : v);
}

// ---------------------------------------------------------------------------
// Weight repack: w[co][ci][t] (fp32) -> wt[t][co_pad][ci_pad] (bf16), zero-pad.
// ---------------------------------------------------------------------------
__global__ __launch_bounds__(256)
void transpose_w(const float* __restrict__ w, ushort* __restrict__ wt,
                 int Cout, int CoutPad, int Cin, int Cin_pad, int KK, int total) {
    int idx = blockIdx.x * 256 + threadIdx.x;
    if (idx >= total) return;
    int ci = idx % Cin_pad;
    int rem = idx / Cin_pad;
    int co = rem % CoutPad;
    int t  = rem / CoutPad;
    float v = (ci < Cin && co < Cout) ? w[((size_t)co * Cin + ci) * KK + t] : 0.f;
    wt[idx] = f2bf(v);
}

// ---------------------------------------------------------------------------
// ConvTranspose weight repack: torch wt[ci][co][ky][kx] -> wtp[t][co][ci_pad]
// ---------------------------------------------------------------------------
__device__ const int g_tky[9] = {1, 1, 1, 0, 2, 0, 0, 2, 2};
__device__ const int g_tkx[9] = {1, 0, 2, 1, 1, 0, 2, 0, 2};

__global__ __launch_bounds__(256)
void transpose_wt(const float* __restrict__ wt, ushort* __restrict__ dst,
                  int Cin, int Cout, int Cin_pad, int total) {
    int idx = blockIdx.x * 256 + threadIdx.x;
    if (idx >= total) return;
    int ci = idx % Cin_pad;
    int rem = idx / Cin_pad;
    int co = rem % Cout;
    int t  = rem / Cout;
    float v = 0.f;
    if (ci < Cin)
        v = wt[((size_t)(ci * Cout + co) * 3 + g_tky[t]) * 3 + g_tkx[t]];
    dst[idx] = f2bf(v);
}

// ---------------------------------------------------------------------------
// conv_mfma9: implicit-GEMM conv, MFMA 16x16x32 bf16.
//  - R10's depth-4 weight A-ring + JIT B ds_reads (proven)
//  - NEW: double-buffered LDS + T14 pipeline:
//      ISSUE(c+1 loads -> regs) ; COMPUTE(c from buf[cur]) ;
//      WAIT+WRITE(c+1 -> buf[cur^1]) ; barrier
//    HBM/L2 load latency hides under the tap loop's MFMAs.
//  - clamped-address loads (W%4==0 required), masks applied at WRITE.
//  - XCD-bijective tile swizzle; split-K -> partial planes (no atomics).
//  - OUTMODE: 0 fp32 plane, 2 bf16 plane.
// ---------------------------------------------------------------------------
template<int K, int TY, int TX, int NSPLIT, int MSPLIT, int MT, int OUTMODE>
__global__ __launch_bounds__(256)
void conv_mfma9(const float* __restrict__ in1, int C1,
                const ushort* __restrict__ in2, int C2, int Cin,
                const ushort* __restrict__ wt,
                void* __restrict__ outDst, size_t pStride,
                int H, int W, int Cout, int CoutPad, int Cin_pad,
                int tilesX, int tilesY, int nchunks, int cps) {
    constexpr int P = K / 2;
    constexpr int XOFF = (K == 1) ? 0 : 4;
    constexpr int JOFF = XOFF - P;
    constexpr int HXs = (TX + K - 1 + JOFF + 3) & ~3;
    constexpr int HY = TY + K - 1;
    constexpr int PITCH = 40;
    constexpr int KK = K * K;
    constexpr int PXW = TY * TX / NSPLIT;
    constexpr int NT = PXW / 16;
    constexpr int G = HXs / 4;
    constexpr int NITEM = 16 * HY * G;
    constexpr int IT = (NITEM + 255) / 256;
    constexpr int LSZ = HY * HXs * PITCH;

    __shared__ ushort sT[2][LSZ];

    const int tid = threadIdx.x;
    const int lane = tid & 63, wv = tid >> 6;
    const int nwave = wv % NSPLIT, mwave = wv / NSPLIT;
    const int l15 = lane & 15, lg = lane >> 4;

    // XCD-bijective swizzle (m204), tiles column-major (y fastest)
    const int nwg = tilesX * tilesY;
    int bid = blockIdx.x;
    int q8 = nwg >> 3, r8 = nwg & 7;
    int xcd = bid & 7, sidx = bid >> 3;
    int wg = (xcd < r8 ? xcd * (q8 + 1) : r8 * (q8 + 1) + (xcd - r8) * q8) + sidx;
    const int txi = wg / tilesY;
    const int tyi = wg % tilesY;

    const int b = blockIdx.z;
    const int x0 = txi * TX, y0 = tyi * TY;
    const size_t HW = (size_t)H * W;

    const int co0 = mwave * (MT * 16);

    int posBase[NT], py_[NT], px_[NT];
    #pragma unroll
    for (int nt = 0; nt < NT; ++nt) {
        int pidx = nwave * PXW + nt * 16 + l15;
        int py = pidx / TX, px = pidx % TX;
        py_[nt] = py; px_[nt] = px;
        posBase[nt] = (py * HXs + px + JOFF) * PITCH + lg * 8;
    }
    const int aoff = l15 * Cin_pad + lg * 8;

    f32x4 acc[MT][NT];
    #pragma unroll
    for (int i = 0; i < MT; ++i)
        #pragma unroll
        for (int j = 0; j < NT; ++j) acc[i][j] = (f32x4)0.f;

    const int c0 = blockIdx.y * cps;
    const int c1 = (c0 + cps < nchunks) ? c0 + cps : nchunks;

    uint4 rA[IT], rB[IT];

    // ---- ISSUE(c): clamped-address global loads into regs ----
    auto ISSUE = [&](int c) {
        const int ci0 = c * 32;
        #pragma unroll
        for (int it = 0; it < IT; ++it) {
            int i = it * 256 + tid;
            int ii = i < NITEM ? i : NITEM - 1;
            int g  = ii % G;
            int rr = (ii / G) % HY;
            int cp = ii / (G * HY);
            int ci = ci0 + cp * 2;
            int yc = iclamp(y0 - P + rr, 0, H - 1);
            int xc = iclamp(x0 - XOFF + g * 4, 0, W - 4);
            if (ci < C1) {
                const float* p = in1 + (long long)(b * C1 + ci) * (long long)HW
                                     + (long long)yc * W + xc;
                rA[it] = *(const uint4*)p;
                rB[it] = *(const uint4*)(p + HW);
            } else {
                int cc = ci - C1; if (cc > C2 - 2) cc = (C2 >= 2 ? C2 - 2 : 0);
                const ushort* qp = in2 + (long long)(b * C2 + cc) * (long long)HW
                                       + (long long)yc * W + xc;
                uint2 a  = *(const uint2*)qp;
                uint2 bb = *(const uint2*)(qp + HW);
                rA[it].x = a.x;  rA[it].y = a.y;
                rB[it].x = bb.x; rB[it].y = bb.y;
            }
        }
    };

    // ---- WRITE(c): mask + pack + rotated LDS stores into buf ----
    auto WRITE = [&](int c, ushort* buf) {
        const int ci0 = c * 32;
        #pragma unroll
        for (int it = 0; it < IT; ++it) {
            int i = it * 256 + tid;
            bool act = i < NITEM;
            int ii = act ? i : NITEM - 1;
            int g  = ii % G;
            int rr = (ii / G) % HY;
            int cp = ii / (G * HY);
            int ci = ci0 + cp * 2;
            int y  = y0 - P + rr;
            int xg = x0 - XOFF + g * 4;
            bool win = ((unsigned)y < (unsigned)H) && (xg >= 0) && (xg + 3 < W);
            bool u1 = (ci < C1);
            bool mA = win && (u1 || ci < Cin);
            bool mB = win && (u1 || (ci + 1) < Cin);
            unsigned d0, d1, d2, d3;
            if (u1) {
                float4 a = *(float4*)&rA[it];
                float4 bb = *(float4*)&rB[it];
                d0 = pack2bf(mA ? a.x : 0.f, mB ? bb.x : 0.f);
                d1 = pack2bf(mA ? a.y : 0.f, mB ? bb.y : 0.f);
                d2 = pack2bf(mA ? a.z : 0.f, mB ? bb.z : 0.f);
                d3 = pack2bf(mA ? a.w : 0.f, mB ? bb.w : 0.f);
            } else {
                unsigned ax = mA ? rA[it].x : 0u, ay = mA ? rA[it].y : 0u;
                unsigned bx = mB ? rB[it].x : 0u, by = mB ? rB[it].y : 0u;
                d0 = (ax & 0xFFFFu) | (bx << 16);
                d1 = (ax >> 16) | (bx & 0xFFFF0000u);
                d2 = (ay & 0xFFFFu) | (by << 16);
                d3 = (ay >> 16) | (by & 0xFFFF0000u);
            }
            if (act) {
                ushort* dp = buf + (rr * HXs + g * 4) * PITCH + cp * 2;
                int s = (g + rr) & 3;
                #pragma unroll
                for (int u = 0; u < 4; ++u) {
                    int cc2 = (u + s) & 3;
                    unsigned val = (cc2 & 2) ? ((cc2 & 1) ? d3 : d2)
                                             : ((cc2 & 1) ? d1 : d0);
                    *(unsigned*)(dp + cc2 * PITCH) = val;
                }
            }
        }
    };

    // ---- prologue: stage chunk c0 ----
    ISSUE(c0);
    WRITE(c0, sT[0]);
    __syncthreads();
    int cur = 0;

    for (int c = c0; c < c1; ++c) {
        const int ci0 = c * 32;
        const bool hasNext = (c + 1 < c1);
        if (hasNext) ISSUE(c + 1);          // loads fly during compute

        // ---- compute chunk c from sT[cur]: depth-4 weight ring ----
        const ushort* bufR = sT[cur];
        bf16x8 af[4][MT];
        #pragma unroll
        for (int s = 0; s < 3; ++s) {
            if (s < KK) {
                const ushort* ap = wt + (size_t)((size_t)s * CoutPad + co0) * Cin_pad + ci0 + aoff;
                #pragma unroll
                for (int mt = 0; mt < MT; ++mt)
                    af[s][mt] = *(const bf16x8*)(ap + (size_t)mt * 16 * Cin_pad);
            }
        }
        #pragma unroll
        for (int t = 0; t < KK; ++t) {
            if (t + 3 < KK) {
                const ushort* ap = wt + (size_t)((size_t)(t + 3) * CoutPad + co0) * Cin_pad + ci0 + aoff;
                #pragma unroll
                for (int mt = 0; mt < MT; ++mt)
                    af[(t + 3) & 3][mt] = *(const bf16x8*)(ap + (size_t)mt * 16 * Cin_pad);
            }
            const int tOff = ((t / K) * HXs + (t % K)) * PITCH;
            bf16x8 bf[NT];
            #pragma unroll
            for (int nt = 0; nt < NT; ++nt)
                bf[nt] = *(const bf16x8*)(bufR + posBase[nt] + tOff);
            #pragma unroll
            for (int mt = 0; mt < MT; ++mt)
                #pragma unroll
                for (int nt = 0; nt < NT; ++nt)
                    acc[mt][nt] = __builtin_amdgcn_mfma_f32_16x16x32_bf16(
                        af[t & 3][mt], bf[nt], acc[mt][nt], 0, 0, 0);
        }

        if (hasNext) WRITE(c + 1, sT[cur ^ 1]);  // waits loads (hidden), writes other buf
        __syncthreads();
        cur ^= 1;
    }

    // ---- store partial plane (plain stores, no atomics) ----
    float*  baseF = (float*)outDst + (size_t)blockIdx.y * pStride;
    ushort* baseU = (ushort*)outDst + (size_t)blockIdx.y * pStride;
    #pragma unroll
    for (int mt = 0; mt < MT; ++mt) {
        #pragma unroll
        for (int nt = 0; nt < NT; ++nt) {
            int y = y0 + py_[nt], x = x0 + px_[nt];
            if (y < H && x < W) {
                #pragma unroll
                for (int r = 0; r < 4; ++r) {
                    int co = co0 + mt * 16 + lg * 4 + r;
                    if (co < Cout) {
                        size_t o = ((size_t)(b * Cout + co)) * HW + (size_t)y * W + x;
                        if (OUTMODE == 0) baseF[o] = acc[mt][nt][r];
                        else              baseU[o] = f2bf(acc[mt][nt][r]);
                    }
                }
            }
        }
    }
}

// ---------------------------------------------------------------------------
// conv_mfma5 — stage-32 only (W=30 not %4; tiny stage, atomics fine).
// ---------------------------------------------------------------------------
template<int K, int TY, int TX, int NSPLIT, int MSPLIT, int MT>
__global__ __launch_bounds__(256)
void conv_mfma5(const float* __restrict__ in1, int C1, int Cin,
                const ushort* __restrict__ wt,
                float* __restrict__ outDst,
                int H, int W, int Cout, int CoutPad, int Cin_pad,
                int tilesX, int nchunks, int cps) {
    constexpr int P = K / 2;
    constexpr int XOFF = 4;
    constexpr int JOFF = XOFF - P;
    constexpr int HXs = (TX + K - 1 + JOFF + 3) & ~3;
    constexpr int HY = TY + K - 1;
    constexpr int PITCH = 40;
    constexpr int KK = K * K;
    constexpr int PXW = TY * TX / NSPLIT;
    constexpr int NT = PXW / 16;
    constexpr int G = HXs / 4;
    constexpr int NITEM = 16 * HY * G;

    __shared__ ushort sT[HY * HXs * PITCH];

    const int tid = threadIdx.x;
    const int lane = tid & 63, wv = tid >> 6;
    const int nwave = wv % NSPLIT, mwave = wv / NSPLIT;
    const int l15 = lane & 15, lg = lane >> 4;

    const int txi = blockIdx.x % tilesX;
    const int tyi = blockIdx.x / tilesX;
    const int b = blockIdx.z;
    const int x0 = txi * TX, y0 = tyi * TY;
    const size_t HW = (size_t)H * W;
    const int co0 = mwave * (MT * 16);

    int posBase[NT], py_[NT], px_[NT];
    #pragma unroll
    for (int nt = 0; nt < NT; ++nt) {
        int pidx = nwave * PXW + nt * 16 + l15;
        int py = pidx / TX, px = pidx % TX;
        py_[nt] = py; px_[nt] = px;
        posBase[nt] = (py * HXs + px + JOFF) * PITCH + lg * 8;
    }
    const int aoff = l15 * Cin_pad + lg * 8;

    f32x4 acc[MT][NT];
    #pragma unroll
    for (int i = 0; i < MT; ++i)
        #pragma unroll
        for (int j = 0; j < NT; ++j) acc[i][j] = (f32x4)0.f;

    const int c0 = blockIdx.y * cps;
    const int c1 = (c0 + cps < nchunks) ? c0 + cps : nchunks;

    for (int c = c0; c < c1; ++c) {
        const int ci0 = c * 32;
        __syncthreads();
        for (int i = tid; i < NITEM; i += 256) {
            int g  = i % G;
            int rr = (i / G) % HY;
            int cp = i / (G * HY);
            int ci = ci0 + cp * 2;
            int y  = y0 - P + rr;
            int xg = x0 - XOFF + g * 4;
            ushort* dp = &sT[(rr * HXs + g * 4) * PITCH + cp * 2];
            const float* p0 = in1 + (long long)(b * C1 + ci) * (long long)HW + (long long)y * W + xg;
            bool yok = (unsigned)y < (unsigned)H;
            #pragma unroll
            for (int u = 0; u < 4; ++u) {
                int x = xg + u;
                unsigned pk = 0;
                if (yok && (unsigned)x < (unsigned)W)
                    pk = (unsigned)f2bf(p0[u]) | ((unsigned)f2bf(p0[u + (long long)HW]) << 16);
                *(unsigned*)(dp + u * PITCH) = pk;
            }
        }
        __syncthreads();

        bf16x8 afA[MT];
        {
            const ushort* ap = wt + (size_t)co0 * Cin_pad + ci0 + aoff;
            #pragma unroll
            for (int mt = 0; mt < MT; ++mt)
                afA[mt] = *(const bf16x8*)(ap + (size_t)mt * 16 * Cin_pad);
        }
        #pragma unroll
        for (int t = 0; t < KK; ++t) {
            bf16x8 afB[MT];
            if (t + 1 < KK) {
                const ushort* ap = wt + (size_t)((t + 1) * CoutPad + co0) * Cin_pad + ci0 + aoff;
                #pragma unroll
                for (int mt = 0; mt < MT; ++mt)
                    afB[mt] = *(const bf16x8*)(ap + (size_t)mt * 16 * Cin_pad);
            }
            const int tOff = ((t / K) * HXs + (t % K)) * PITCH;
            bf16x8 bf[NT];
            #pragma unroll
            for (int nt = 0; nt < NT; ++nt)
                bf[nt] = *(const bf16x8*)(sT + posBase[nt] + tOff);
            #pragma unroll
            for (int mt = 0; mt < MT; ++mt)
                #pragma unroll
                for (int nt = 0; nt < NT; ++nt)
                    acc[mt][nt] = __builtin_amdgcn_mfma_f32_16x16x32_bf16(
                        afA[mt], bf[nt], acc[mt][nt], 0, 0, 0);
            if (t + 1 < KK) {
                #pragma unroll
                for (int mt = 0; mt < MT; ++mt) afA[mt] = afB[mt];
            }
        }
    }

    #pragma unroll
    for (int mt = 0; mt < MT; ++mt) {
        #pragma unroll
        for (int nt = 0; nt < NT; ++nt) {
            int y = y0 + py_[nt], x = x0 + px_[nt];
            if (y < H && x < W) {
                #pragma unroll
                for (int r = 0; r < 4; ++r) {
                    int co = co0 + mt * 16 + lg * 4 + r;
                    if (co < Cout) {
                        size_t o = ((size_t)(b * Cout + co)) * HW + (size_t)y * W + x;
                        unsafeAtomicAdd(&outDst[o], acc[mt][nt][r]);
                    }
                }
            }
        }
    }
}

// ---------------------------------------------------------------------------
// ConvTranspose2d k3/s2/p1/op1 via MFMA, 4-phase subpixel decomposition.
// ---------------------------------------------------------------------------
template<int TY, int TX, int NSPLIT, int MT>
__global__ __launch_bounds__(256)
void convt_mfma(const float* __restrict__ in,
                const ushort* __restrict__ wtp,
                ushort* __restrict__ out,
                int Cin, int Cout, int Cin_pad, int Hin, int Win,
                int tilesX, int tilesY) {
    constexpr int HY = TY + 1, HX = TX + 1;
    constexpr int PITCH = 40;
    constexpr int NPX = TY * TX;
    constexpr int PXW = NPX / NSPLIT;
    constexpr int NT = PXW / 16;
    constexpr int NPOS = HY * HX;
    constexpr int NIT = (NPOS * 16 + 63) & ~63;

    __shared__ ushort sT[NPOS * PITCH];

    constexpr int toy[9] = {0, 0, 0, 1, 0, 1, 1, 0, 0};
    constexpr int tox[9] = {0, 1, 0, 0, 0, 1, 0, 1, 0};
    constexpr int tph[9] = {0, 1, 1, 2, 2, 3, 3, 3, 3};

    const int tid = threadIdx.x;
    const int lane = tid & 63, wv = tid >> 6;
    const int nwave = wv % NSPLIT, mwave = wv / NSPLIT;
    const int l15 = lane & 15, lg = lane >> 4;

    int tile = blockIdx.x;
    const int txi = tile % tilesX;
    int rem = tile / tilesX;
    const int tyi = rem % tilesY;
    const int b = rem / tilesY;
    const int x0 = txi * TX, y0 = tyi * TY;
    const size_t HWi = (size_t)Hin * Win;
    const int Wo = 2 * Win;
    const size_t HWo = (size_t)4 * HWi;

    const int co0 = mwave * (MT * 16);

    int posBase[NT], py_[NT], px_[NT];
    #pragma unroll
    for (int nt = 0; nt < NT; ++nt) {
        int pidx = nwave * PXW + nt * 16 + l15;
        int py = pidx / TX, px = pidx % TX;
        py_[nt] = py; px_[nt] = px;
        posBase[nt] = (py * HX + px) * PITCH + lg * 8;
    }
    const int aoff = l15 * Cin_pad + lg * 8;

    f32x4 acc[4][MT][NT];
    #pragma unroll
    for (int p = 0; p < 4; ++p)
        #pragma unroll
        for (int i = 0; i < MT; ++i)
            #pragma unroll
            for (int j = 0; j < NT; ++j) acc[p][i][j] = (f32x4)0.f;

    const int nchunks = Cin_pad / 32;
    for (int c = 0; c < nchunks; ++c) {
        const int ci0 = c * 32;
        __syncthreads();
        for (int i = tid; i < NIT; i += 256) {
            int cp = (i >> 2) & 15;
            int pos = (i & 3) | ((i >> 6) << 2);
            if (pos < NPOS) {
                int hy = pos / HX, hx = pos % HX;
                int y = y0 + hy, x = x0 + hx;
                int ci = ci0 + cp * 2;
                unsigned pk = 0;
                if ((unsigned)y < (unsigned)Hin && (unsigned)x < (unsigned)Win && ci < Cin) {
                    const float* p0 = in + (size_t)(b * Cin + ci) * HWi + (size_t)y * Win + x;
                    float v0 = p0[0];
                    float v1 = (ci + 1 < Cin) ? p0[HWi] : 0.f;
                    pk = pack2bf(v0, v1);
                }
                *(unsigned*)&sT[pos * PITCH + cp * 2] = pk;
            }
        }
        __syncthreads();

        bf16x8 afA[MT];
        {
            const ushort* ap = wtp + (size_t)co0 * Cin_pad + ci0 + aoff;
            #pragma unroll
            for (int mt = 0; mt < MT; ++mt)
                afA[mt] = *(const bf16x8*)(ap + (size_t)mt * 16 * Cin_pad);
        }
        #pragma unroll
        for (int t = 0; t < 9; ++t) {
            bf16x8 afB[MT];
            if (t + 1 < 9) {
                const ushort* ap = wtp + (size_t)((t + 1) * Cout + co0) * Cin_pad + ci0 + aoff;
                #pragma unroll
                for (int mt = 0; mt < MT; ++mt)
                    afB[mt] = *(const bf16x8*)(ap + (size_t)mt * 16 * Cin_pad);
            }
            const int tOff = (toy[t] * HX + tox[t]) * PITCH;
            bf16x8 bf[NT];
            #pragma unroll
            for (int nt = 0; nt < NT; ++nt)
                bf[nt] = *(const bf16x8*)(sT + posBase[nt] + tOff);
            #pragma unroll
            for (int mt = 0; mt < MT; ++mt)
                #pragma unroll
                for (int nt = 0; nt < NT; ++nt)
                    acc[tph[t]][mt][nt] = __builtin_amdgcn_mfma_f32_16x16x32_bf16(
                        afA[mt], bf[nt], acc[tph[t]][mt][nt], 0, 0, 0);
            if (t + 1 < 9) {
                #pragma unroll
                for (int mt = 0; mt < MT; ++mt) afA[mt] = afB[mt];
            }
        }
    }

    #pragma unroll
    for (int dy = 0; dy < 2; ++dy) {
        #pragma unroll
        for (int mt = 0; mt < MT; ++mt) {
            #pragma unroll
            for (int nt = 0; nt < NT; ++nt) {
                int y = y0 + py_[nt], x = x0 + px_[nt];
                if (y < Hin && x < Win) {
                    #pragma unroll
                    for (int r = 0; r < 4; ++r) {
                        int co = co0 + mt * 16 + lg * 4 + r;
                        unsigned pk = pack2bf(acc[dy * 2][mt][nt][r], acc[dy * 2 + 1][mt][nt][r]);
                        *(unsigned*)&out[((size_t)(b * Cout + co)) * HWo + (size_t)(2 * y + dy) * Wo + 2 * x] = pk;
                    }
                }
            }
        }
    }
}

// ---------------------------------------------------------------------------
// InstanceNorm stats over NS fp32 partial planes.
// ---------------------------------------------------------------------------
__global__ __launch_bounds__(256)
void inorm_stats2(const float* __restrict__ x, size_t pStride, int NS,
                  float* __restrict__ mean, float* __restrict__ istd, int HW) {
    int bc = blockIdx.x;
    const float4* p = (const float4*)(x + (size_t)bc * HW);
    size_t st4 = pStride >> 2;
    int n4 = HW >> 2;
    float s = 0.f, ss = 0.f;
    for (int i = threadIdx.x; i < n4; i += 256) {
        float4 v = p[i];
        for (int sp = 1; sp < NS; ++sp) {
            float4 w = p[i + sp * st4];
            v.x += w.x; v.y += w.y; v.z += w.z; v.w += w.w;
        }
        s += v.x + v.y + v.z + v.w;
        ss += v.x * v.x + v.y * v.y + v.z * v.z + v.w * v.w;
    }
    #pragma unroll
    for (int o = 32; o > 0; o >>= 1) {
        s  += __shfl_down(s, o);
        ss += __shfl_down(ss, o);
    }
    __shared__ float sh[4][2];
    int wid = threadIdx.x >> 6, ln = threadIdx.x & 63;
    if (ln == 0) { sh[wid][0] = s; sh[wid][1] = ss; }
    __syncthreads();
    if (threadIdx.x == 0) {
        float S = 0.f, SS = 0.f;
        for (int i = 0; i < 4; ++i) { S += sh[i][0]; SS += sh[i][1]; }
        float m = S / HW;
        float v = SS / HW - m * m;
        v = v > 0.f ? v : 0.f;
        mean[bc] = m;
        istd[bc] = rsqrtf(v + 1e-5f);
    }
}

// ---------------------------------------------------------------------------
// Epilogue over fp32 partial planes: feat = relu((Σraw - m)*istd) [+ Σres + br]
// RESMODE: 0 none, 1 fp32 res planes, 2 bf16 res single plane.
// ---------------------------------------------------------------------------
template<int RESMODE>
__global__ __launch_bounds__(256)
void epilogue2(const float* __restrict__ raw, size_t rawStride, int NS,
               const float* __restrict__ mean,
               const float* __restrict__ istd,
               const void* __restrict__ res, size_t resStride, int NSR,
               const float* __restrict__ br,
               float* __restrict__ feat,
               int HW, int Cout, int total4) {
    int i = blockIdx.x * 256 + threadIdx.x;
    if (i >= total4) return;
    int bc = (int)(((long long)i * 4) / HW);
    float m = mean[bc], is = istd[bc];
    size_t rs4 = rawStride >> 2;
    float4 r = ((const float4*)raw)[i];
    for (int sp = 1; sp < NS; ++sp) {
        float4 w = ((const float4*)raw)[i + sp * rs4];
        r.x += w.x; r.y += w.y; r.z += w.z; r.w += w.w;
    }
    float4 o;
    o.x = fmaxf((r.x - m) * is, 0.f);
    o.y = fmaxf((r.y - m) * is, 0.f);
    o.z = fmaxf((r.z - m) * is, 0.f);
    o.w = fmaxf((r.w - m) * is, 0.f);
    if (RESMODE == 1) {
        float bb = br[bc % Cout];
        size_t es4 = resStride >> 2;
        float4 e = ((const float4*)res)[i];
        for (int sp = 1; sp < NSR; ++sp) {
            float4 w = ((const float4*)res)[i + sp * es4];
            e.x += w.x; e.y += w.y; e.z += w.z; e.w += w.w;
        }
        o.x += e.x + bb; o.y += e.y + bb; o.z += e.z + bb; o.w += e.w + bb;
    } else if (RESMODE == 2) {
        float bb = br[bc % Cout];
        ushort4 e = ((const ushort4*)res)[i];
        o.x += bf2f(e.x) + bb; o.y += bf2f(e.y) + bb;
        o.z += bf2f(e.z) + bb; o.w += bf2f(e.w) + bb;
    }
    ((float4*)feat)[i] = o;
}

extern "C" void kernel_launch(void* const* d_in, const int* in_sizes, int n_in,
                              void* d_out, int out_size, void* d_ws, size_t ws_size,
                              hipStream_t stream) {
    const float* f4   = (const float*)d_in[0];
    const float* f8   = (const float*)d_in[1];
    const float* f16  = (const float*)d_in[2];
    const float* f32  = (const float*)d_in[3];
    const float* w32  = (const float*)d_in[4];
    const float* wt32 = (const float*)d_in[6];
    const float* w16  = (const float*)d_in[7];
    const float* wr16 = (const float*)d_in[9];
    const float* br16 = (const float*)d_in[10];
    const float* wt16 = (const float*)d_in[11];
    const float* w8   = (const float*)d_in[12];
    const float* wr8  = (const float*)d_in[14];
    const float* br8  = (const float*)d_in[15];
    const float* wt8  = (const float*)d_in[16];
    const float* w4   = (const float*)d_in[17];
    const float* wr4  = (const float*)d_in[19];
    const float* br4  = (const float*)d_in[20];
    // main-conv biases cancel under InstanceNorm -> unused.

    float* out = (float*)d_out;

    const int B = 2, C = 256;
    const int H4 = 160, W4 = 240;
    const int H8 = 80,  W8 = 120;
    const int H16 = 40, W16 = 60;
    const int H32 = 20, W32 = 30;

    float* feat4  = out;
    float* feat8  = out + (size_t)B * 48 * H4 * W4;
    float* feat16 = feat8 + (size_t)B * 64 * H8 * W8;
    float* feat32 = feat16 + (size_t)B * 192 * H16 * W16;

    // ws (R10 layout): wsUpB bf16 (7.4MB) | wsRawP fp32 partial planes (14.7MB)
    //                  | wsResB bf16 / wsResF fp32 partials (7.4MB) | stats
    const size_t bufElems = (size_t)B * 48 * H4 * W4;  // 3,686,400
    ushort* wsUpB  = (ushort*)d_ws;
    float*  wsRawP = (float*)(wsUpB + bufElems);
    ushort* wsResB = (ushort*)(wsRawP + bufElems);
    float*  stMean = (float*)(wsResB + bufElems);
    float*  stIstd = stMean + 512;
    float*  wsResF = (float*)wsResB;

    // bf16 repacked weights in the feat4 output region (written last).
    ushort* wb = (ushort*)feat4;
    ushort* W32p = wb;                          // 9*192*256
    ushort* W16p = W32p + 9 * 192 * 256;        // 25*192*448
    ushort* W8p  = W16p + 25 * 192 * 448;       // 25*64*320
    ushort* W4p  = W8p  + 25 * 64 * 320;        // 25*64*320 (Cout pad 48->64)
    ushort* R16p = W4p  + 25 * 64 * 320;        // 192*256
    ushort* R8p  = R16p + 192 * 256;            // 64*256
    ushort* R4p  = R8p  + 64 * 256;             // 64*256 (pad)
    ushort* T32p = R4p  + 64 * 256;             // 9*192*160
    ushort* T16p = T32p + 9 * 192 * 160;        // 9*64*192
    ushort* T8p  = T16p + 9 * 64 * 192;         // 9*48*64

    // ---- weight repacks ----
    {
        int t1 = 9 * 192 * 256;
        transpose_w<<<cdiv(t1, 256), 256, 0, stream>>>(w32, W32p, 160, 192, 256, 256, 9, t1);
        int t2 = 25 * 192 * 448;
        transpose_w<<<cdiv(t2, 256), 256, 0, stream>>>(w16, W16p, 192, 192, 448, 448, 25, t2);
        int t3 = 25 * 64 * 320;
        transpose_w<<<cdiv(t3, 256), 256, 0, stream>>>(w8, W8p, 64, 64, 320, 320, 25, t3);
        int t4 = 25 * 64 * 320;
        transpose_w<<<cdiv(t4, 256), 256, 0, stream>>>(w4, W4p, 48, 64, 304, 320, 25, t4);
        int t5 = 192 * 256;
        transpose_w<<<cdiv(t5, 256), 256, 0, stream>>>(wr16, R16p, 192, 192, 256, 256, 1, t5);
        int t6 = 64 * 256;
        transpose_w<<<cdiv(t6, 256), 256, 0, stream>>>(wr8, R8p, 64, 64, 256, 256, 1, t6);
        int t7 = 64 * 256;
        transpose_w<<<cdiv(t7, 256), 256, 0, stream>>>(wr4, R4p, 48, 64, 256, 256, 1, t7);
        int u1 = 9 * 192 * 160;
        transpose_wt<<<cdiv(u1, 256), 256, 0, stream>>>(wt32, T32p, 160, 192, 160, u1);
        int u2 = 9 * 64 * 192;
        transpose_wt<<<cdiv(u2, 256), 256, 0, stream>>>(wt16, T16p, 192, 64, 192, u2);
        int u3 = 9 * 48 * 64;
        transpose_wt<<<cdiv(u3, 256), 256, 0, stream>>>(wt8, T8p, 64, 48, 64, u3);
    }

    // ---------------- stage 32 (K=3, Cin=256, Cout=160, 20x30) ----------------
    {
        hipMemsetAsync(wsRawP, 0, (size_t)B * 160 * H32 * W32 * 4, stream);
        int tX = cdiv(W32, 8), tY = cdiv(H32, 4);   // 4 x 5
        dim3 g(tX * tY, 8, B);
        conv_mfma5<3, 4, 8, 1, 4, 3><<<g, 256, 0, stream>>>(
            f32, C, C, W32p, wsRawP, H32, W32, 160, 192, 256, tX, 8, 1);
        inorm_stats2<<<B * 160, 256, 0, stream>>>(wsRawP, 0, 1, stMean, stIstd, H32 * W32);
        int tot4 = B * 160 * H32 * W32 / 4;
        epilogue2<0><<<cdiv(tot4, 256), 256, 0, stream>>>(
            wsRawP, 0, 1, stMean, stIstd, nullptr, 0, 0, nullptr, feat32, H32 * W32, 160, tot4);
        int uX = cdiv(W32, 8), uY = cdiv(H32, 2);
        convt_mfma<2, 8, 1, 3><<<uX * uY * B, 256, 0, stream>>>(
            feat32, T32p, wsUpB, 160, 192, 160, H32, W32, uX, uY);
    }
    // ---------------- stage 16 (K=5, Cin=256+192, Cout=192, 40x60) ------------
    {
        size_t SZ16 = (size_t)B * 192 * H16 * W16;  // 921,600
        int tX = cdiv(W16, 8), tY = cdiv(H16, 4);   // 8 x 10 = 80 tiles
        dim3 g(tX * tY, 4, B);                       // KSPLIT=4 -> 640 blocks
        conv_mfma9<5, 4, 8, 1, 4, 3, 0><<<g, 256, 0, stream>>>(
            f16, C, wsUpB, 192, 448, W16p, wsRawP, SZ16,
            H16, W16, 192, 192, 448, tX, tY, 14, 4);
        dim3 gr(tX * tY, 2, B);                      // res KSPLIT=2 fp32 planes
        conv_mfma9<1, 4, 8, 1, 4, 3, 0><<<gr, 256, 0, stream>>>(
            f16, C, nullptr, 0, C, R16p, wsResF, SZ16,
            H16, W16, 192, 192, 256, tX, tY, 8, 4);
        inorm_stats2<<<B * 192, 256, 0, stream>>>(wsRawP, SZ16, 4, stMean, stIstd, H16 * W16);
        int tot4 = (int)(SZ16 / 4);
        epilogue2<1><<<cdiv(tot4, 256), 256, 0, stream>>>(
            wsRawP, SZ16, 4, stMean, stIstd, wsResF, SZ16, 2, br16, feat16, H16 * W16, 192, tot4);
        int uX = cdiv(W16, 8), uY = cdiv(H16, 4);
        convt_mfma<4, 8, 2, 2><<<uX * uY * B, 256, 0, stream>>>(
            feat16, T16p, wsUpB, 192, 64, 192, H16, W16, uX, uY);
    }
    // ---------------- stage 8 (K=5, Cin=256+64, Cout=64, 80x120) --------------
    {
        size_t SZ8 = (size_t)B * 64 * H8 * W8;      // 1,228,800
        int tX = cdiv(W8, 16), tY = cdiv(H8, 8);    // 8 x 10
        dim3 g(tX * tY, 3, B);                       // KSPLIT=3 planes (4,4,2)
        conv_mfma9<5, 8, 16, 2, 2, 2, 0><<<g, 256, 0, stream>>>(
            f8, C, wsUpB, 64, 320, W8p, wsRawP, SZ8,
            H8, W8, 64, 64, 320, tX, tY, 10, 4);
        dim3 gr(tX * cdiv(H8, 4), 1, B);             // res: TY=4 -> 160 tiles
        conv_mfma9<1, 4, 16, 1, 4, 1, 0><<<gr, 256, 0, stream>>>(
            f8, C, nullptr, 0, C, R8p, wsResF, SZ8,
            H8, W8, 64, 64, 256, tX, cdiv(H8, 4), 8, 8);
        inorm_stats2<<<B * 64, 256, 0, stream>>>(wsRawP, SZ8, 3, stMean, stIstd, H8 * W8);
        int tot4 = (int)(SZ8 / 4);
        epilogue2<1><<<cdiv(tot4, 256), 256, 0, stream>>>(
            wsRawP, SZ8, 3, stMean, stIstd, wsResF, SZ8, 1, br8, feat8, H8 * W8, 64, tot4);
        int uX = cdiv(W8, 16), uY = cdiv(H8, 4);
        convt_mfma<4, 16, 4, 3><<<uX * uY * B, 256, 0, stream>>>(
            feat8, T8p, wsUpB, 64, 48, 64, H8, W8, uX, uY);
    }
    // ---------------- stage 4 (K=5, Cin=256+48, Cout=48->64pad, 160x240) ------
    {
        size_t SZ4 = (size_t)B * 48 * H4 * W4;      // 3,686,400
        int tX = cdiv(W4, 16), tY = cdiv(H4, 8);    // 15 x 20 = 300 tiles
        dim3 g(tX * tY, 1, B);                       // KSPLIT=1 -> 600 blocks
        conv_mfma9<5, 8, 16, 2, 2, 2, 0><<<g, 256, 0, stream>>>(
            f4, C, wsUpB, 48, 304, W4p, wsRawP, SZ4,
            H4, W4, 48, 64, 320, tX, tY, 10, 10);
        conv_mfma9<1, 8, 16, 2, 2, 2, 2><<<g, 256, 0, stream>>>(
            f4, C, nullptr, 0, C, R4p, wsResB, 0,
            H4, W4, 48, 64, 256, tX, tY, 8, 8);
        inorm_stats2<<<B * 48, 256, 0, stream>>>(wsRawP, 0, 1, stMean, stIstd, H4 * W4);
        int tot4 = (int)(SZ4 / 4);
        epilogue2<2><<<cdiv(tot4, 256), 256, 0, stream>>>(
            wsRawP, 0, 1, stMean, stIstd, wsResB, 0, 0, br4, feat4, H4 * W4, 48, tot4);
    }
}

// Round 14
// 580.849 us; speedup vs baseline: 1.1963x; 1.1963x over previous
//
#include <hip/hip_runtime.h>
#include <hip/hip_bf16.h>

typedef __attribute__((ext_vector_type(8))) short bf16x8;
typedef __attribute__((ext_vector_type(4))) float f32x4;

static inline int cdiv(int a, int b) { return (a + b - 1) / b; }

__device__ __forceinline__ ushort f2bf(float f) {
    unsigned u = __float_as_uint(f);
    unsigned r = (u + 0x7FFFu + ((u >> 16) & 1u)) >> 16;
    return (ushort)r;
}
__device__ __forceinline__ unsigned pack2bf(float lo, float hi) {
    unsigned r;
    asm("v_cvt_pk_bf16_f32 %0, %1, %2" : "=v"(r) : "v"(lo), "v"(hi));
    return r;
}
__device__ __forceinline__ float bf2f(ushort u) {
    return __uint_as_float((unsigned)u << 16);
}

// ---------------------------------------------------------------------------
// Weight repack: w[co][ci][t] (fp32) -> wt[t][co_pad][ci_pad] (bf16), zero-pad.
// ---------------------------------------------------------------------------
__global__ __launch_bounds__(256)
void transpose_w(const float* __restrict__ w, ushort* __restrict__ wt,
                 int Cout, int CoutPad, int Cin, int Cin_pad, int KK, int total) {
    int idx = blockIdx.x * 256 + threadIdx.x;
    if (idx >= total) return;
    int ci = idx % Cin_pad;
    int rem = idx / Cin_pad;
    int co = rem % CoutPad;
    int t  = rem / CoutPad;
    float v = (ci < Cin && co < Cout) ? w[((size_t)co * Cin + ci) * KK + t] : 0.f;
    wt[idx] = f2bf(v);
}

// ---------------------------------------------------------------------------
// ConvTranspose weight repack: torch wt[ci][co][ky][kx] -> wtp[t][co][ci_pad]
// ---------------------------------------------------------------------------
__device__ const int g_tky[9] = {1, 1, 1, 0, 2, 0, 0, 2, 2};
__device__ const int g_tkx[9] = {1, 0, 2, 1, 1, 0, 2, 0, 2};

__global__ __launch_bounds__(256)
void transpose_wt(const float* __restrict__ wt, ushort* __restrict__ dst,
                  int Cin, int Cout, int Cin_pad, int total) {
    int idx = blockIdx.x * 256 + threadIdx.x;
    if (idx >= total) return;
    int ci = idx % Cin_pad;
    int rem = idx / Cin_pad;
    int co = rem % Cout;
    int t  = rem / Cout;
    float v = 0.f;
    if (ci < Cin)
        v = wt[((size_t)(ci * Cout + co) * 3 + g_tky[t]) * 3 + g_tkx[t]];
    dst[idx] = f2bf(v);
}

// ---------------------------------------------------------------------------
// conv_mfma10: R10's proven structure with 64-ci chunks.
//  - depth-4 weight A-ring over VIRTUAL taps (tap t, K-slice ks): NVT = 2*K*K
//  - JIT B ds_reads per vtap (R11's B-ring regressed -> not used)
//  - direct staging, g-fastest coalesced, rotated LDS writes
//  - chunk = 64 ci (PITCH=72): HALVES barrier phases, doubles per-phase MLP
//    and MFMA work; LDS 41.5KB -> 3 blocks/CU (>= grid limit, no occ loss)
//  - XCD-bijective tile swizzle; split-K -> partial planes (no atomics)
//  - OUTMODE: 0 fp32 plane, 2 bf16 plane.  nchunks/cps in 64-ci units.
// ---------------------------------------------------------------------------
template<int K, int TY, int TX, int NSPLIT, int MSPLIT, int MT, int OUTMODE>
__global__ __launch_bounds__(256)
void conv_mfma10(const float* __restrict__ in1, int C1,
                 const ushort* __restrict__ in2, int C2, int Cin,
                 const ushort* __restrict__ wt,
                 void* __restrict__ outDst, size_t pStride,
                 int H, int W, int Cout, int CoutPad, int Cin_pad,
                 int tilesX, int tilesY, int nchunks, int cps) {
    constexpr int P = K / 2;
    constexpr int XOFF = (K == 1) ? 0 : 4;
    constexpr int JOFF = XOFF - P;
    constexpr int HXs = (TX + K - 1 + JOFF + 3) & ~3;
    constexpr int HY = TY + K - 1;
    constexpr int PITCH = 72;            // 64 ci + 8 pad (ushorts)
    constexpr int KK = K * K;
    constexpr int NVT = 2 * KK;          // virtual taps (tap x K-slice)
    constexpr int PXW = TY * TX / NSPLIT;
    constexpr int NT = PXW / 16;
    constexpr int G = HXs / 4;
    constexpr int NITEM = 32 * HY * G;   // cp in 0..31 (pairs)

    __shared__ ushort sT[HY * HXs * PITCH];

    const int tid = threadIdx.x;
    const int lane = tid & 63, wv = tid >> 6;
    const int nwave = wv % NSPLIT, mwave = wv / NSPLIT;
    const int l15 = lane & 15, lg = lane >> 4;

    // XCD-bijective swizzle (m204), tiles column-major (y fastest)
    const int nwg = tilesX * tilesY;
    int bid = blockIdx.x;
    int q8 = nwg >> 3, r8 = nwg & 7;
    int xcd = bid & 7, sidx = bid >> 3;
    int wg = (xcd < r8 ? xcd * (q8 + 1) : r8 * (q8 + 1) + (xcd - r8) * q8) + sidx;
    const int txi = wg / tilesY;
    const int tyi = wg % tilesY;

    const int b = blockIdx.z;
    const int x0 = txi * TX, y0 = tyi * TY;
    const size_t HW = (size_t)H * W;

    const int co0 = mwave * (MT * 16);

    int posBase[NT], py_[NT], px_[NT];
    #pragma unroll
    for (int nt = 0; nt < NT; ++nt) {
        int pidx = nwave * PXW + nt * 16 + l15;
        int py = pidx / TX, px = pidx % TX;
        py_[nt] = py; px_[nt] = px;
        posBase[nt] = (py * HXs + px + JOFF) * PITCH + lg * 8;
    }
    const int aoff = l15 * Cin_pad + lg * 8;

    f32x4 acc[MT][NT];
    #pragma unroll
    for (int i = 0; i < MT; ++i)
        #pragma unroll
        for (int j = 0; j < NT; ++j) acc[i][j] = (f32x4)0.f;

    const int c0 = blockIdx.y * cps;
    const int c1 = (c0 + cps < nchunks) ? c0 + cps : nchunks;

    for (int c = c0; c < c1; ++c) {
        const int ci0 = c * 64;
        __syncthreads();
        // ---- stage 64-ci halo tile: g-fastest (coalesced), rotated writes ----
        #pragma unroll 3
        for (int i = tid; i < NITEM; i += 256) {
            int g  = i % G;
            int rr = (i / G) % HY;
            int cp = i / (G * HY);
            int ci = ci0 + cp * 2;
            int y  = y0 - P + rr;
            int xg = x0 - XOFF + g * 4;
            ushort* dp = &sT[(rr * HXs + g * 4) * PITCH + cp * 2];
            bool yok = (unsigned)y < (unsigned)H;
            unsigned d0, d1, d2, d3;
            if (ci < C1) {
                const float* p0 = in1 + (long long)(b * C1 + ci) * (long long)HW + (long long)y * W + xg;
                if (yok && xg >= 0 && (xg + 3) < W) {
                    float4 a  = *(const float4*)p0;
                    float4 b2 = *(const float4*)(p0 + HW);
                    d0 = pack2bf(a.x, b2.x);
                    d1 = pack2bf(a.y, b2.y);
                    d2 = pack2bf(a.z, b2.z);
                    d3 = pack2bf(a.w, b2.w);
                } else {
                    unsigned t0 = 0, t1 = 0, t2 = 0, t3 = 0;
                    #pragma unroll
                    for (int u = 0; u < 4; ++u) {
                        int x = xg + u;
                        unsigned pk = 0;
                        if (yok && (unsigned)x < (unsigned)W)
                            pk = (unsigned)f2bf(p0[u]) | ((unsigned)f2bf(p0[u + (long long)HW]) << 16);
                        if (u == 0) t0 = pk; else if (u == 1) t1 = pk;
                        else if (u == 2) t2 = pk; else t3 = pk;
                    }
                    d0 = t0; d1 = t1; d2 = t2; d3 = t3;
                }
            } else {
                const ushort* q0 = in2 + (long long)(b * C2 + (ci - C1)) * (long long)HW + (long long)y * W + xg;
                if (yok && xg >= 0 && (xg + 3) < W && (ci + 1) < Cin) {
                    ushort4 a  = *(const ushort4*)q0;
                    ushort4 b2 = *(const ushort4*)(q0 + HW);
                    d0 = (unsigned)a.x | ((unsigned)b2.x << 16);
                    d1 = (unsigned)a.y | ((unsigned)b2.y << 16);
                    d2 = (unsigned)a.z | ((unsigned)b2.z << 16);
                    d3 = (unsigned)a.w | ((unsigned)b2.w << 16);
                } else {
                    unsigned t0 = 0, t1 = 0, t2 = 0, t3 = 0;
                    #pragma unroll
                    for (int u = 0; u < 4; ++u) {
                        int x = xg + u;
                        unsigned pk = 0;
                        if (yok && (unsigned)x < (unsigned)W && ci < Cin) {
                            unsigned v0 = q0[u];
                            unsigned v1 = (ci + 1 < Cin) ? q0[u + (long long)HW] : 0u;
                            pk = v0 | (v1 << 16);
                        }
                        if (u == 0) t0 = pk; else if (u == 1) t1 = pk;
                        else if (u == 2) t2 = pk; else t3 = pk;
                    }
                    d0 = t0; d1 = t1; d2 = t2; d3 = t3;
                }
            }
            int s = (g + rr) & 3;
            #pragma unroll
            for (int u = 0; u < 4; ++u) {
                int cc2 = (u + s) & 3;
                unsigned val = (cc2 & 2) ? ((cc2 & 1) ? d3 : d2)
                                         : ((cc2 & 1) ? d1 : d0);
                *(unsigned*)(dp + cc2 * PITCH) = val;
            }
        }
        __syncthreads();

        // ---- depth-4 weight ring over NVT virtual taps ----
        bf16x8 af[4][MT];
        #pragma unroll
        for (int s = 0; s < 3; ++s) {
            if (s < NVT) {
                const int t = s >> 1, ks = s & 1;
                const ushort* ap = wt + (size_t)((size_t)t * CoutPad + co0) * Cin_pad
                                      + ci0 + ks * 32 + aoff;
                #pragma unroll
                for (int mt = 0; mt < MT; ++mt)
                    af[s][mt] = *(const bf16x8*)(ap + (size_t)mt * 16 * Cin_pad);
            }
        }
        #pragma unroll
        for (int tt = 0; tt < NVT; ++tt) {
            if (tt + 3 < NVT) {
                const int tn = (tt + 3) >> 1, ksn = (tt + 3) & 1;
                const ushort* ap = wt + (size_t)((size_t)tn * CoutPad + co0) * Cin_pad
                                      + ci0 + ksn * 32 + aoff;
                #pragma unroll
                for (int mt = 0; mt < MT; ++mt)
                    af[(tt + 3) & 3][mt] = *(const bf16x8*)(ap + (size_t)mt * 16 * Cin_pad);
            }
            const int t = tt >> 1, ks = tt & 1;
            const int tOff = ((t / K) * HXs + (t % K)) * PITCH + ks * 32;
            bf16x8 bf[NT];
            #pragma unroll
            for (int nt = 0; nt < NT; ++nt)
                bf[nt] = *(const bf16x8*)(sT + posBase[nt] + tOff);
            #pragma unroll
            for (int mt = 0; mt < MT; ++mt)
                #pragma unroll
                for (int nt = 0; nt < NT; ++nt)
                    acc[mt][nt] = __builtin_amdgcn_mfma_f32_16x16x32_bf16(
                        af[tt & 3][mt], bf[nt], acc[mt][nt], 0, 0, 0);
        }
    }

    // ---- store partial plane (plain stores, no atomics) ----
    float*  baseF = (float*)outDst + (size_t)blockIdx.y * pStride;
    ushort* baseU = (ushort*)outDst + (size_t)blockIdx.y * pStride;
    #pragma unroll
    for (int mt = 0; mt < MT; ++mt) {
        #pragma unroll
        for (int nt = 0; nt < NT; ++nt) {
            int y = y0 + py_[nt], x = x0 + px_[nt];
            if (y < H && x < W) {
                #pragma unroll
                for (int r = 0; r < 4; ++r) {
                    int co = co0 + mt * 16 + lg * 4 + r;
                    if (co < Cout) {
                        size_t o = ((size_t)(b * Cout + co)) * HW + (size_t)y * W + x;
                        if (OUTMODE == 0) baseF[o] = acc[mt][nt][r];
                        else              baseU[o] = f2bf(acc[mt][nt][r]);
                    }
                }
            }
        }
    }
}

// ---------------------------------------------------------------------------
// conv_mfma5 — stage-32 only (W=30 not %4; tiny stage, atomics fine).
// ---------------------------------------------------------------------------
template<int K, int TY, int TX, int NSPLIT, int MSPLIT, int MT>
__global__ __launch_bounds__(256)
void conv_mfma5(const float* __restrict__ in1, int C1, int Cin,
                const ushort* __restrict__ wt,
                float* __restrict__ outDst,
                int H, int W, int Cout, int CoutPad, int Cin_pad,
                int tilesX, int nchunks, int cps) {
    constexpr int P = K / 2;
    constexpr int XOFF = 4;
    constexpr int JOFF = XOFF - P;
    constexpr int HXs = (TX + K - 1 + JOFF + 3) & ~3;
    constexpr int HY = TY + K - 1;
    constexpr int PITCH = 40;
    constexpr int KK = K * K;
    constexpr int PXW = TY * TX / NSPLIT;
    constexpr int NT = PXW / 16;
    constexpr int G = HXs / 4;
    constexpr int NITEM = 16 * HY * G;

    __shared__ ushort sT[HY * HXs * PITCH];

    const int tid = threadIdx.x;
    const int lane = tid & 63, wv = tid >> 6;
    const int nwave = wv % NSPLIT, mwave = wv / NSPLIT;
    const int l15 = lane & 15, lg = lane >> 4;

    const int txi = blockIdx.x % tilesX;
    const int tyi = blockIdx.x / tilesX;
    const int b = blockIdx.z;
    const int x0 = txi * TX, y0 = tyi * TY;
    const size_t HW = (size_t)H * W;
    const int co0 = mwave * (MT * 16);

    int posBase[NT], py_[NT], px_[NT];
    #pragma unroll
    for (int nt = 0; nt < NT; ++nt) {
        int pidx = nwave * PXW + nt * 16 + l15;
        int py = pidx / TX, px = pidx % TX;
        py_[nt] = py; px_[nt] = px;
        posBase[nt] = (py * HXs + px + JOFF) * PITCH + lg * 8;
    }
    const int aoff = l15 * Cin_pad + lg * 8;

    f32x4 acc[MT][NT];
    #pragma unroll
    for (int i = 0; i < MT; ++i)
        #pragma unroll
        for (int j = 0; j < NT; ++j) acc[i][j] = (f32x4)0.f;

    const int c0 = blockIdx.y * cps;
    const int c1 = (c0 + cps < nchunks) ? c0 + cps : nchunks;

    for (int c = c0; c < c1; ++c) {
        const int ci0 = c * 32;
        __syncthreads();
        for (int i = tid; i < NITEM; i += 256) {
            int g  = i % G;
            int rr = (i / G) % HY;
            int cp = i / (G * HY);
            int ci = ci0 + cp * 2;
            int y  = y0 - P + rr;
            int xg = x0 - XOFF + g * 4;
            ushort* dp = &sT[(rr * HXs + g * 4) * PITCH + cp * 2];
            const float* p0 = in1 + (long long)(b * C1 + ci) * (long long)HW + (long long)y * W + xg;
            bool yok = (unsigned)y < (unsigned)H;
            #pragma unroll
            for (int u = 0; u < 4; ++u) {
                int x = xg + u;
                unsigned pk = 0;
                if (yok && (unsigned)x < (unsigned)W)
                    pk = (unsigned)f2bf(p0[u]) | ((unsigned)f2bf(p0[u + (long long)HW]) << 16);
                *(unsigned*)(dp + u * PITCH) = pk;
            }
        }
        __syncthreads();

        bf16x8 afA[MT];
        {
            const ushort* ap = wt + (size_t)co0 * Cin_pad + ci0 + aoff;
            #pragma unroll
            for (int mt = 0; mt < MT; ++mt)
                afA[mt] = *(const bf16x8*)(ap + (size_t)mt * 16 * Cin_pad);
        }
        #pragma unroll
        for (int t = 0; t < KK; ++t) {
            bf16x8 afB[MT];
            if (t + 1 < KK) {
                const ushort* ap = wt + (size_t)((t + 1) * CoutPad + co0) * Cin_pad + ci0 + aoff;
                #pragma unroll
                for (int mt = 0; mt < MT; ++mt)
                    afB[mt] = *(const bf16x8*)(ap + (size_t)mt * 16 * Cin_pad);
            }
            const int tOff = ((t / K) * HXs + (t % K)) * PITCH;
            bf16x8 bf[NT];
            #pragma unroll
            for (int nt = 0; nt < NT; ++nt)
                bf[nt] = *(const bf16x8*)(sT + posBase[nt] + tOff);
            #pragma unroll
            for (int mt = 0; mt < MT; ++mt)
                #pragma unroll
                for (int nt = 0; nt < NT; ++nt)
                    acc[mt][nt] = __builtin_amdgcn_mfma_f32_16x16x32_bf16(
                        afA[mt], bf[nt], acc[mt][nt], 0, 0, 0);
            if (t + 1 < KK) {
                #pragma unroll
                for (int mt = 0; mt < MT; ++mt) afA[mt] = afB[mt];
            }
        }
    }

    #pragma unroll
    for (int mt = 0; mt < MT; ++mt) {
        #pragma unroll
        for (int nt = 0; nt < NT; ++nt) {
            int y = y0 + py_[nt], x = x0 + px_[nt];
            if (y < H && x < W) {
                #pragma unroll
                for (int r = 0; r < 4; ++r) {
                    int co = co0 + mt * 16 + lg * 4 + r;
                    if (co < Cout) {
                        size_t o = ((size_t)(b * Cout + co)) * HW + (size_t)y * W + x;
                        unsafeAtomicAdd(&outDst[o], acc[mt][nt][r]);
                    }
                }
            }
        }
    }
}

// ---------------------------------------------------------------------------
// ConvTranspose2d k3/s2/p1/op1 via MFMA, 4-phase subpixel decomposition.
// ---------------------------------------------------------------------------
template<int TY, int TX, int NSPLIT, int MT>
__global__ __launch_bounds__(256)
void convt_mfma(const float* __restrict__ in,
                const ushort* __restrict__ wtp,
                ushort* __restrict__ out,
                int Cin, int Cout, int Cin_pad, int Hin, int Win,
                int tilesX, int tilesY) {
    constexpr int HY = TY + 1, HX = TX + 1;
    constexpr int PITCH = 40;
    constexpr int NPX = TY * TX;
    constexpr int PXW = NPX / NSPLIT;
    constexpr int NT = PXW / 16;
    constexpr int NPOS = HY * HX;
    constexpr int NIT = (NPOS * 16 + 63) & ~63;

    __shared__ ushort sT[NPOS * PITCH];

    constexpr int toy[9] = {0, 0, 0, 1, 0, 1, 1, 0, 0};
    constexpr int tox[9] = {0, 1, 0, 0, 0, 1, 0, 1, 0};
    constexpr int tph[9] = {0, 1, 1, 2, 2, 3, 3, 3, 3};

    const int tid = threadIdx.x;
    const int lane = tid & 63, wv = tid >> 6;
    const int nwave = wv % NSPLIT, mwave = wv / NSPLIT;
    const int l15 = lane & 15, lg = lane >> 4;

    int tile = blockIdx.x;
    const int txi = tile % tilesX;
    int rem = tile / tilesX;
    const int tyi = rem % tilesY;
    const int b = rem / tilesY;
    const int x0 = txi * TX, y0 = tyi * TY;
    const size_t HWi = (size_t)Hin * Win;
    const int Wo = 2 * Win;
    const size_t HWo = (size_t)4 * HWi;

    const int co0 = mwave * (MT * 16);

    int posBase[NT], py_[NT], px_[NT];
    #pragma unroll
    for (int nt = 0; nt < NT; ++nt) {
        int pidx = nwave * PXW + nt * 16 + l15;
        int py = pidx / TX, px = pidx % TX;
        py_[nt] = py; px_[nt] = px;
        posBase[nt] = (py * HX + px) * PITCH + lg * 8;
    }
    const int aoff = l15 * Cin_pad + lg * 8;

    f32x4 acc[4][MT][NT];
    #pragma unroll
    for (int p = 0; p < 4; ++p)
        #pragma unroll
        for (int i = 0; i < MT; ++i)
            #pragma unroll
            for (int j = 0; j < NT; ++j) acc[p][i][j] = (f32x4)0.f;

    const int nchunks = Cin_pad / 32;
    for (int c = 0; c < nchunks; ++c) {
        const int ci0 = c * 32;
        __syncthreads();
        for (int i = tid; i < NIT; i += 256) {
            int cp = (i >> 2) & 15;
            int pos = (i & 3) | ((i >> 6) << 2);
            if (pos < NPOS) {
                int hy = pos / HX, hx = pos % HX;
                int y = y0 + hy, x = x0 + hx;
                int ci = ci0 + cp * 2;
                unsigned pk = 0;
                if ((unsigned)y < (unsigned)Hin && (unsigned)x < (unsigned)Win && ci < Cin) {
                    const float* p0 = in + (size_t)(b * Cin + ci) * HWi + (size_t)y * Win + x;
                    float v0 = p0[0];
                    float v1 = (ci + 1 < Cin) ? p0[HWi] : 0.f;
                    pk = pack2bf(v0, v1);
                }
                *(unsigned*)&sT[pos * PITCH + cp * 2] = pk;
            }
        }
        __syncthreads();

        bf16x8 afA[MT];
        {
            const ushort* ap = wtp + (size_t)co0 * Cin_pad + ci0 + aoff;
            #pragma unroll
            for (int mt = 0; mt < MT; ++mt)
                afA[mt] = *(const bf16x8*)(ap + (size_t)mt * 16 * Cin_pad);
        }
        #pragma unroll
        for (int t = 0; t < 9; ++t) {
            bf16x8 afB[MT];
            if (t + 1 < 9) {
                const ushort* ap = wtp + (size_t)((t + 1) * Cout + co0) * Cin_pad + ci0 + aoff;
                #pragma unroll
                for (int mt = 0; mt < MT; ++mt)
                    afB[mt] = *(const bf16x8*)(ap + (size_t)mt * 16 * Cin_pad);
            }
            const int tOff = (toy[t] * HX + tox[t]) * PITCH;
            bf16x8 bf[NT];
            #pragma unroll
            for (int nt = 0; nt < NT; ++nt)
                bf[nt] = *(const bf16x8*)(sT + posBase[nt] + tOff);
            #pragma unroll
            for (int mt = 0; mt < MT; ++mt)
                #pragma unroll
                for (int nt = 0; nt < NT; ++nt)
                    acc[tph[t]][mt][nt] = __builtin_amdgcn_mfma_f32_16x16x32_bf16(
                        afA[mt], bf[nt], acc[tph[t]][mt][nt], 0, 0, 0);
            if (t + 1 < 9) {
                #pragma unroll
                for (int mt = 0; mt < MT; ++mt) afA[mt] = afB[mt];
            }
        }
    }

    #pragma unroll
    for (int dy = 0; dy < 2; ++dy) {
        #pragma unroll
        for (int mt = 0; mt < MT; ++mt) {
            #pragma unroll
            for (int nt = 0; nt < NT; ++nt) {
                int y = y0 + py_[nt], x = x0 + px_[nt];
                if (y < Hin && x < Win) {
                    #pragma unroll
                    for (int r = 0; r < 4; ++r) {
                        int co = co0 + mt * 16 + lg * 4 + r;
                        unsigned pk = pack2bf(acc[dy * 2][mt][nt][r], acc[dy * 2 + 1][mt][nt][r]);
                        *(unsigned*)&out[((size_t)(b * Cout + co)) * HWo + (size_t)(2 * y + dy) * Wo + 2 * x] = pk;
                    }
                }
            }
        }
    }
}

// ---------------------------------------------------------------------------
// InstanceNorm stats over NS fp32 partial planes.
// ---------------------------------------------------------------------------
__global__ __launch_bounds__(256)
void inorm_stats2(const float* __restrict__ x, size_t pStride, int NS,
                  float* __restrict__ mean, float* __restrict__ istd, int HW) {
    int bc = blockIdx.x;
    const float4* p = (const float4*)(x + (size_t)bc * HW);
    size_t st4 = pStride >> 2;
    int n4 = HW >> 2;
    float s = 0.f, ss = 0.f;
    for (int i = threadIdx.x; i < n4; i += 256) {
        float4 v = p[i];
        for (int sp = 1; sp < NS; ++sp) {
            float4 w = p[i + sp * st4];
            v.x += w.x; v.y += w.y; v.z += w.z; v.w += w.w;
        }
        s += v.x + v.y + v.z + v.w;
        ss += v.x * v.x + v.y * v.y + v.z * v.z + v.w * v.w;
    }
    #pragma unroll
    for (int o = 32; o > 0; o >>= 1) {
        s  += __shfl_down(s, o);
        ss += __shfl_down(ss, o);
    }
    __shared__ float sh[4][2];
    int wid = threadIdx.x >> 6, ln = threadIdx.x & 63;
    if (ln == 0) { sh[wid][0] = s; sh[wid][1] = ss; }
    __syncthreads();
    if (threadIdx.x == 0) {
        float S = 0.f, SS = 0.f;
        for (int i = 0; i < 4; ++i) { S += sh[i][0]; SS += sh[i][1]; }
        float m = S / HW;
        float v = SS / HW - m * m;
        v = v > 0.f ? v : 0.f;
        mean[bc] = m;
        istd[bc] = rsqrtf(v + 1e-5f);
    }
}

// ---------------------------------------------------------------------------
// Epilogue over fp32 partial planes: feat = relu((Σraw - m)*istd) [+ Σres + br]
// RESMODE: 0 none, 1 fp32 res planes, 2 bf16 res single plane.
// ---------------------------------------------------------------------------
template<int RESMODE>
__global__ __launch_bounds__(256)
void epilogue2(const float* __restrict__ raw, size_t rawStride, int NS,
               const float* __restrict__ mean,
               const float* __restrict__ istd,
               const void* __restrict__ res, size_t resStride, int NSR,
               const float* __restrict__ br,
               float* __restrict__ feat,
               int HW, int Cout, int total4) {
    int i = blockIdx.x * 256 + threadIdx.x;
    if (i >= total4) return;
    int bc = (int)(((long long)i * 4) / HW);
    float m = mean[bc], is = istd[bc];
    size_t rs4 = rawStride >> 2;
    float4 r = ((const float4*)raw)[i];
    for (int sp = 1; sp < NS; ++sp) {
        float4 w = ((const float4*)raw)[i + sp * rs4];
        r.x += w.x; r.y += w.y; r.z += w.z; r.w += w.w;
    }
    float4 o;
    o.x = fmaxf((r.x - m) * is, 0.f);
    o.y = fmaxf((r.y - m) * is, 0.f);
    o.z = fmaxf((r.z - m) * is, 0.f);
    o.w = fmaxf((r.w - m) * is, 0.f);
    if (RESMODE == 1) {
        float bb = br[bc % Cout];
        size_t es4 = resStride >> 2;
        float4 e = ((const float4*)res)[i];
        for (int sp = 1; sp < NSR; ++sp) {
            float4 w = ((const float4*)res)[i + sp * es4];
            e.x += w.x; e.y += w.y; e.z += w.z; e.w += w.w;
        }
        o.x += e.x + bb; o.y += e.y + bb; o.z += e.z + bb; o.w += e.w + bb;
    } else if (RESMODE == 2) {
        float bb = br[bc % Cout];
        ushort4 e = ((const ushort4*)res)[i];
        o.x += bf2f(e.x) + bb; o.y += bf2f(e.y) + bb;
        o.z += bf2f(e.z) + bb; o.w += bf2f(e.w) + bb;
    }
    ((float4*)feat)[i] = o;
}

extern "C" void kernel_launch(void* const* d_in, const int* in_sizes, int n_in,
                              void* d_out, int out_size, void* d_ws, size_t ws_size,
                              hipStream_t stream) {
    const float* f4   = (const float*)d_in[0];
    const float* f8   = (const float*)d_in[1];
    const float* f16  = (const float*)d_in[2];
    const float* f32  = (const float*)d_in[3];
    const float* w32  = (const float*)d_in[4];
    const float* wt32 = (const float*)d_in[6];
    const float* w16  = (const float*)d_in[7];
    const float* wr16 = (const float*)d_in[9];
    const float* br16 = (const float*)d_in[10];
    const float* wt16 = (const float*)d_in[11];
    const float* w8   = (const float*)d_in[12];
    const float* wr8  = (const float*)d_in[14];
    const float* br8  = (const float*)d_in[15];
    const float* wt8  = (const float*)d_in[16];
    const float* w4   = (const float*)d_in[17];
    const float* wr4  = (const float*)d_in[19];
    const float* br4  = (const float*)d_in[20];
    // main-conv biases cancel under InstanceNorm -> unused.

    float* out = (float*)d_out;

    const int B = 2, C = 256;
    const int H4 = 160, W4 = 240;
    const int H8 = 80,  W8 = 120;
    const int H16 = 40, W16 = 60;
    const int H32 = 20, W32 = 30;

    float* feat4  = out;
    float* feat8  = out + (size_t)B * 48 * H4 * W4;
    float* feat16 = feat8 + (size_t)B * 64 * H8 * W8;
    float* feat32 = feat16 + (size_t)B * 192 * H16 * W16;

    // ws (R10 layout): wsUpB bf16 (7.4MB) | wsRawP fp32 partial planes (14.7MB)
    //                  | wsResB bf16 / wsResF fp32 partials (7.4MB) | stats
    const size_t bufElems = (size_t)B * 48 * H4 * W4;  // 3,686,400
    ushort* wsUpB  = (ushort*)d_ws;
    float*  wsRawP = (float*)(wsUpB + bufElems);
    ushort* wsResB = (ushort*)(wsRawP + bufElems);
    float*  stMean = (float*)(wsResB + bufElems);
    float*  stIstd = stMean + 512;
    float*  wsResF = (float*)wsResB;

    // bf16 repacked weights in the feat4 output region (written last).
    ushort* wb = (ushort*)feat4;
    ushort* W32p = wb;                          // 9*192*256
    ushort* W16p = W32p + 9 * 192 * 256;        // 25*192*448
    ushort* W8p  = W16p + 25 * 192 * 448;       // 25*64*320
    ushort* W4p  = W8p  + 25 * 64 * 320;        // 25*64*320 (Cout pad 48->64)
    ushort* R16p = W4p  + 25 * 64 * 320;        // 192*256
    ushort* R8p  = R16p + 192 * 256;            // 64*256
    ushort* R4p  = R8p  + 64 * 256;             // 64*256 (pad)
    ushort* T32p = R4p  + 64 * 256;             // 9*192*160
    ushort* T16p = T32p + 9 * 192 * 160;        // 9*64*192
    ushort* T8p  = T16p + 9 * 64 * 192;         // 9*48*64

    // ---- weight repacks ----
    {
        int t1 = 9 * 192 * 256;
        transpose_w<<<cdiv(t1, 256), 256, 0, stream>>>(w32, W32p, 160, 192, 256, 256, 9, t1);
        int t2 = 25 * 192 * 448;
        transpose_w<<<cdiv(t2, 256), 256, 0, stream>>>(w16, W16p, 192, 192, 448, 448, 25, t2);
        int t3 = 25 * 64 * 320;
        transpose_w<<<cdiv(t3, 256), 256, 0, stream>>>(w8, W8p, 64, 64, 320, 320, 25, t3);
        int t4 = 25 * 64 * 320;
        transpose_w<<<cdiv(t4, 256), 256, 0, stream>>>(w4, W4p, 48, 64, 304, 320, 25, t4);
        int t5 = 192 * 256;
        transpose_w<<<cdiv(t5, 256), 256, 0, stream>>>(wr16, R16p, 192, 192, 256, 256, 1, t5);
        int t6 = 64 * 256;
        transpose_w<<<cdiv(t6, 256), 256, 0, stream>>>(wr8, R8p, 64, 64, 256, 256, 1, t6);
        int t7 = 64 * 256;
        transpose_w<<<cdiv(t7, 256), 256, 0, stream>>>(wr4, R4p, 48, 64, 256, 256, 1, t7);
        int u1 = 9 * 192 * 160;
        transpose_wt<<<cdiv(u1, 256), 256, 0, stream>>>(wt32, T32p, 160, 192, 160, u1);
        int u2 = 9 * 64 * 192;
        transpose_wt<<<cdiv(u2, 256), 256, 0, stream>>>(wt16, T16p, 192, 64, 192, u2);
        int u3 = 9 * 48 * 64;
        transpose_wt<<<cdiv(u3, 256), 256, 0, stream>>>(wt8, T8p, 64, 48, 64, u3);
    }

    // ---------------- stage 32 (K=3, Cin=256, Cout=160, 20x30) ----------------
    {
        hipMemsetAsync(wsRawP, 0, (size_t)B * 160 * H32 * W32 * 4, stream);
        int tX = cdiv(W32, 8), tY = cdiv(H32, 4);   // 4 x 5
        dim3 g(tX * tY, 8, B);
        conv_mfma5<3, 4, 8, 1, 4, 3><<<g, 256, 0, stream>>>(
            f32, C, C, W32p, wsRawP, H32, W32, 160, 192, 256, tX, 8, 1);
        inorm_stats2<<<B * 160, 256, 0, stream>>>(wsRawP, 0, 1, stMean, stIstd, H32 * W32);
        int tot4 = B * 160 * H32 * W32 / 4;
        epilogue2<0><<<cdiv(tot4, 256), 256, 0, stream>>>(
            wsRawP, 0, 1, stMean, stIstd, nullptr, 0, 0, nullptr, feat32, H32 * W32, 160, tot4);
        int uX = cdiv(W32, 8), uY = cdiv(H32, 2);
        convt_mfma<2, 8, 1, 3><<<uX * uY * B, 256, 0, stream>>>(
            feat32, T32p, wsUpB, 160, 192, 160, H32, W32, uX, uY);
    }
    // ---------------- stage 16 (K=5, Cin=256+192, Cout=192, 40x60) ------------
    {
        size_t SZ16 = (size_t)B * 192 * H16 * W16;  // 921,600
        int tX = cdiv(W16, 8), tY = cdiv(H16, 4);   // 8 x 10 = 80 tiles
        dim3 g(tX * tY, 4, B);                       // KSPLIT=4 over 7 chunks64
        conv_mfma10<5, 4, 8, 1, 4, 3, 0><<<g, 256, 0, stream>>>(
            f16, C, wsUpB, 192, 448, W16p, wsRawP, SZ16,
            H16, W16, 192, 192, 448, tX, tY, 7, 2);
        dim3 gr(tX * tY, 2, B);                      // res KSPLIT=2 over 4 chunks64
        conv_mfma10<1, 4, 8, 1, 4, 3, 0><<<gr, 256, 0, stream>>>(
            f16, C, nullptr, 0, C, R16p, wsResF, SZ16,
            H16, W16, 192, 192, 256, tX, tY, 4, 2);
        inorm_stats2<<<B * 192, 256, 0, stream>>>(wsRawP, SZ16, 4, stMean, stIstd, H16 * W16);
        int tot4 = (int)(SZ16 / 4);
        epilogue2<1><<<cdiv(tot4, 256), 256, 0, stream>>>(
            wsRawP, SZ16, 4, stMean, stIstd, wsResF, SZ16, 2, br16, feat16, H16 * W16, 192, tot4);
        int uX = cdiv(W16, 8), uY = cdiv(H16, 4);
        convt_mfma<4, 8, 2, 2><<<uX * uY * B, 256, 0, stream>>>(
            feat16, T16p, wsUpB, 192, 64, 192, H16, W16, uX, uY);
    }
    // ---------------- stage 8 (K=5, Cin=256+64, Cout=64, 80x120) --------------
    {
        size_t SZ8 = (size_t)B * 64 * H8 * W8;      // 1,228,800
        int tX = cdiv(W8, 16), tY = cdiv(H8, 8);    // 8 x 10
        dim3 g(tX * tY, 3, B);                       // KSPLIT=3 over 5 chunks64
        conv_mfma10<5, 8, 16, 2, 2, 2, 0><<<g, 256, 0, stream>>>(
            f8, C, wsUpB, 64, 320, W8p, wsRawP, SZ8,
            H8, W8, 64, 64, 320, tX, tY, 5, 2);
        dim3 gr(tX * cdiv(H8, 4), 1, B);             // res: TY=4 -> 160 tiles
        conv_mfma10<1, 4, 16, 1, 4, 1, 0><<<gr, 256, 0, stream>>>(
            f8, C, nullptr, 0, C, R8p, wsResF, SZ8,
            H8, W8, 64, 64, 256, tX, cdiv(H8, 4), 4, 4);
        inorm_stats2<<<B * 64, 256, 0, stream>>>(wsRawP, SZ8, 3, stMean, stIstd, H8 * W8);
        int tot4 = (int)(SZ8 / 4);
        epilogue2<1><<<cdiv(tot4, 256), 256, 0, stream>>>(
            wsRawP, SZ8, 3, stMean, stIstd, wsResF, SZ8, 1, br8, feat8, H8 * W8, 64, tot4);
        int uX = cdiv(W8, 16), uY = cdiv(H8, 4);
        convt_mfma<4, 16, 4, 3><<<uX * uY * B, 256, 0, stream>>>(
            feat8, T8p, wsUpB, 64, 48, 64, H8, W8, uX, uY);
    }
    // ---------------- stage 4 (K=5, Cin=256+48, Cout=48->64pad, 160x240) ------
    {
        size_t SZ4 = (size_t)B * 48 * H4 * W4;      // 3,686,400
        int tX = cdiv(W4, 16), tY = cdiv(H4, 8);    // 15 x 20 = 300 tiles
        dim3 g(tX * tY, 1, B);                       // KSPLIT=1 -> 600 blocks
        conv_mfma10<5, 8, 16, 2, 2, 2, 0><<<g, 256, 0, stream>>>(
            f4, C, wsUpB, 48, 304, W4p, wsRawP, SZ4,
            H4, W4, 48, 64, 320, tX, tY, 5, 5);
        conv_mfma10<1, 8, 16, 2, 2, 2, 2><<<g, 256, 0, stream>>>(
            f4, C, nullptr, 0, C, R4p, wsResB, 0,
            H4, W4, 48, 64, 256, tX, tY, 4, 4);
        inorm_stats2<<<B * 48, 256, 0, stream>>>(wsRawP, 0, 1, stMean, stIstd, H4 * W4);
        int tot4 = (int)(SZ4 / 4);
        epilogue2<2><<<cdiv(tot4, 256), 256, 0, stream>>>(
            wsRawP, 0, 1, stMean, stIstd, wsResB, 0, 0, br4, feat4, H4 * W4, 48, tot4);
    }
}

// Round 15
// 566.451 us; speedup vs baseline: 1.2267x; 1.0254x over previous
//
#include <hip/hip_runtime.h>
#include <hip/hip_bf16.h>

typedef __attribute__((ext_vector_type(8))) short bf16x8;
typedef __attribute__((ext_vector_type(4))) float f32x4;

static inline int cdiv(int a, int b) { return (a + b - 1) / b; }

__device__ __forceinline__ ushort f2bf(float f) {
    unsigned u = __float_as_uint(f);
    unsigned r = (u + 0x7FFFu + ((u >> 16) & 1u)) >> 16;
    return (ushort)r;
}
__device__ __forceinline__ unsigned pack2bf(float lo, float hi) {
    unsigned r;
    asm("v_cvt_pk_bf16_f32 %0, %1, %2" : "=v"(r) : "v"(lo), "v"(hi));
    return r;
}
__device__ __forceinline__ float bf2f(ushort u) {
    return __uint_as_float((unsigned)u << 16);
}

constexpr int ldsElems(int K, int TY, int TX) {
    int P = K / 2;
    int XOFF = (K == 1) ? 0 : 4;
    int JOFF = XOFF - P;
    int HXs = (TX + K - 1 + JOFF + 3) & ~3;
    int HY = TY + K - 1;
    return HY * HXs * 72;
}
constexpr int imax(int a, int b) { return a > b ? a : b; }

// ---------------------------------------------------------------------------
// Weight repack: w[co][ci][t] (fp32) -> wt[t][co_pad][ci_pad] (bf16), zero-pad.
// ---------------------------------------------------------------------------
__global__ __launch_bounds__(256)
void transpose_w(const float* __restrict__ w, ushort* __restrict__ wt,
                 int Cout, int CoutPad, int Cin, int Cin_pad, int KK, int total) {
    int idx = blockIdx.x * 256 + threadIdx.x;
    if (idx >= total) return;
    int ci = idx % Cin_pad;
    int rem = idx / Cin_pad;
    int co = rem % CoutPad;
    int t  = rem / CoutPad;
    float v = (ci < Cin && co < Cout) ? w[((size_t)co * Cin + ci) * KK + t] : 0.f;
    wt[idx] = f2bf(v);
}

// ---------------------------------------------------------------------------
// ConvTranspose weight repack: torch wt[ci][co][ky][kx] -> wtp[t][co][ci_pad]
// ---------------------------------------------------------------------------
__device__ const int g_tky[9] = {1, 1, 1, 0, 2, 0, 0, 2, 2};
__device__ const int g_tkx[9] = {1, 0, 2, 1, 1, 0, 2, 0, 2};

__global__ __launch_bounds__(256)
void transpose_wt(const float* __restrict__ wt, ushort* __restrict__ dst,
                  int Cin, int Cout, int Cin_pad, int total) {
    int idx = blockIdx.x * 256 + threadIdx.x;
    if (idx >= total) return;
    int ci = idx % Cin_pad;
    int rem = idx / Cin_pad;
    int co = rem % Cout;
    int t  = rem / Cout;
    float v = 0.f;
    if (ci < Cin)
        v = wt[((size_t)(ci * Cout + co) * 3 + g_tky[t]) * 3 + g_tkx[t]];
    dst[idx] = f2bf(v);
}

// ---------------------------------------------------------------------------
// conv_body: R14's proven conv_mfma10 structure as a device function.
//  - 64-ci chunks (PITCH=72), depth-4 weight ring over 2*K*K virtual taps,
//    JIT B ds_reads, g-fastest coalesced staging, rotated LDS writes,
//    XCD-bijective tile swizzle, partial-plane split-K (ySlot).
//  - OUTMODE: 0 fp32 plane, 2 bf16 plane.
// ---------------------------------------------------------------------------
template<int K, int TY, int TX, int NSPLIT, int MSPLIT, int MT, int OUTMODE>
__device__ __forceinline__
void conv_body(ushort* sT,
               const float* __restrict__ in1, int C1,
               const ushort* __restrict__ in2, int C2, int Cin,
               const ushort* __restrict__ wt,
               void* __restrict__ outDst, size_t pStride, int ySlot,
               int H, int W, int Cout, int CoutPad, int Cin_pad,
               int tilesX, int tilesY, int nchunks, int cps) {
    constexpr int P = K / 2;
    constexpr int XOFF = (K == 1) ? 0 : 4;
    constexpr int JOFF = XOFF - P;
    constexpr int HXs = (TX + K - 1 + JOFF + 3) & ~3;
    constexpr int HY = TY + K - 1;
    constexpr int PITCH = 72;            // 64 ci + 8 pad (ushorts)
    constexpr int KK = K * K;
    constexpr int NVT = 2 * KK;          // virtual taps (tap x K-slice)
    constexpr int PXW = TY * TX / NSPLIT;
    constexpr int NT = PXW / 16;
    constexpr int G = HXs / 4;
    constexpr int NITEM = 32 * HY * G;

    const int tid = threadIdx.x;
    const int lane = tid & 63, wv = tid >> 6;
    const int nwave = wv % NSPLIT, mwave = wv / NSPLIT;
    const int l15 = lane & 15, lg = lane >> 4;

    // XCD-bijective swizzle, tiles column-major (y fastest)
    const int nwg = tilesX * tilesY;
    int bid = blockIdx.x;
    int q8 = nwg >> 3, r8 = nwg & 7;
    int xcd = bid & 7, sidx = bid >> 3;
    int wg = (xcd < r8 ? xcd * (q8 + 1) : r8 * (q8 + 1) + (xcd - r8) * q8) + sidx;
    const int txi = wg / tilesY;
    const int tyi = wg % tilesY;

    const int b = blockIdx.z;
    const int x0 = txi * TX, y0 = tyi * TY;
    const size_t HW = (size_t)H * W;

    const int co0 = mwave * (MT * 16);

    int posBase[NT], py_[NT], px_[NT];
    #pragma unroll
    for (int nt = 0; nt < NT; ++nt) {
        int pidx = nwave * PXW + nt * 16 + l15;
        int py = pidx / TX, px = pidx % TX;
        py_[nt] = py; px_[nt] = px;
        posBase[nt] = (py * HXs + px + JOFF) * PITCH + lg * 8;
    }
    const int aoff = l15 * Cin_pad + lg * 8;

    f32x4 acc[MT][NT];
    #pragma unroll
    for (int i = 0; i < MT; ++i)
        #pragma unroll
        for (int j = 0; j < NT; ++j) acc[i][j] = (f32x4)0.f;

    const int c0 = ySlot * cps;
    const int c1 = (c0 + cps < nchunks) ? c0 + cps : nchunks;

    for (int c = c0; c < c1; ++c) {
        const int ci0 = c * 64;
        __syncthreads();
        // ---- stage 64-ci halo tile ----
        #pragma unroll 3
        for (int i = tid; i < NITEM; i += 256) {
            int g  = i % G;
            int rr = (i / G) % HY;
            int cp = i / (G * HY);
            int ci = ci0 + cp * 2;
            int y  = y0 - P + rr;
            int xg = x0 - XOFF + g * 4;
            ushort* dp = &sT[(rr * HXs + g * 4) * PITCH + cp * 2];
            bool yok = (unsigned)y < (unsigned)H;
            unsigned d0, d1, d2, d3;
            if (ci < C1) {
                const float* p0 = in1 + (long long)(b * C1 + ci) * (long long)HW + (long long)y * W + xg;
                if (yok && xg >= 0 && (xg + 3) < W) {
                    float4 a  = *(const float4*)p0;
                    float4 b2 = *(const float4*)(p0 + HW);
                    d0 = pack2bf(a.x, b2.x);
                    d1 = pack2bf(a.y, b2.y);
                    d2 = pack2bf(a.z, b2.z);
                    d3 = pack2bf(a.w, b2.w);
                } else {
                    unsigned t0 = 0, t1 = 0, t2 = 0, t3 = 0;
                    #pragma unroll
                    for (int u = 0; u < 4; ++u) {
                        int x = xg + u;
                        unsigned pk = 0;
                        if (yok && (unsigned)x < (unsigned)W)
                            pk = (unsigned)f2bf(p0[u]) | ((unsigned)f2bf(p0[u + (long long)HW]) << 16);
                        if (u == 0) t0 = pk; else if (u == 1) t1 = pk;
                        else if (u == 2) t2 = pk; else t3 = pk;
                    }
                    d0 = t0; d1 = t1; d2 = t2; d3 = t3;
                }
            } else {
                const ushort* q0 = in2 + (long long)(b * C2 + (ci - C1)) * (long long)HW + (long long)y * W + xg;
                if (yok && xg >= 0 && (xg + 3) < W && (ci + 1) < Cin) {
                    ushort4 a  = *(const ushort4*)q0;
                    ushort4 b2 = *(const ushort4*)(q0 + HW);
                    d0 = (unsigned)a.x | ((unsigned)b2.x << 16);
                    d1 = (unsigned)a.y | ((unsigned)b2.y << 16);
                    d2 = (unsigned)a.z | ((unsigned)b2.z << 16);
                    d3 = (unsigned)a.w | ((unsigned)b2.w << 16);
                } else {
                    unsigned t0 = 0, t1 = 0, t2 = 0, t3 = 0;
                    #pragma unroll
                    for (int u = 0; u < 4; ++u) {
                        int x = xg + u;
                        unsigned pk = 0;
                        if (yok && (unsigned)x < (unsigned)W && ci < Cin) {
                            unsigned v0 = q0[u];
                            unsigned v1 = (ci + 1 < Cin) ? q0[u + (long long)HW] : 0u;
                            pk = v0 | (v1 << 16);
                        }
                        if (u == 0) t0 = pk; else if (u == 1) t1 = pk;
                        else if (u == 2) t2 = pk; else t3 = pk;
                    }
                    d0 = t0; d1 = t1; d2 = t2; d3 = t3;
                }
            }
            int s = (g + rr) & 3;
            #pragma unroll
            for (int u = 0; u < 4; ++u) {
                int cc2 = (u + s) & 3;
                unsigned val = (cc2 & 2) ? ((cc2 & 1) ? d3 : d2)
                                         : ((cc2 & 1) ? d1 : d0);
                *(unsigned*)(dp + cc2 * PITCH) = val;
            }
        }
        __syncthreads();

        // ---- depth-4 weight ring over NVT virtual taps ----
        bf16x8 af[4][MT];
        #pragma unroll
        for (int s = 0; s < 3; ++s) {
            if (s < NVT) {
                const int t = s >> 1, ks = s & 1;
                const ushort* ap = wt + (size_t)((size_t)t * CoutPad + co0) * Cin_pad
                                      + ci0 + ks * 32 + aoff;
                #pragma unroll
                for (int mt = 0; mt < MT; ++mt)
                    af[s][mt] = *(const bf16x8*)(ap + (size_t)mt * 16 * Cin_pad);
            }
        }
        #pragma unroll
        for (int tt = 0; tt < NVT; ++tt) {
            if (tt + 3 < NVT) {
                const int tn = (tt + 3) >> 1, ksn = (tt + 3) & 1;
                const ushort* ap = wt + (size_t)((size_t)tn * CoutPad + co0) * Cin_pad
                                      + ci0 + ksn * 32 + aoff;
                #pragma unroll
                for (int mt = 0; mt < MT; ++mt)
                    af[(tt + 3) & 3][mt] = *(const bf16x8*)(ap + (size_t)mt * 16 * Cin_pad);
            }
            const int t = tt >> 1, ks = tt & 1;
            const int tOff = ((t / K) * HXs + (t % K)) * PITCH + ks * 32;
            bf16x8 bf[NT];
            #pragma unroll
            for (int nt = 0; nt < NT; ++nt)
                bf[nt] = *(const bf16x8*)(sT + posBase[nt] + tOff);
            #pragma unroll
            for (int mt = 0; mt < MT; ++mt)
                #pragma unroll
                for (int nt = 0; nt < NT; ++nt)
                    acc[mt][nt] = __builtin_amdgcn_mfma_f32_16x16x32_bf16(
                        af[tt & 3][mt], bf[nt], acc[mt][nt], 0, 0, 0);
        }
    }

    // ---- store partial plane ----
    float*  baseF = (float*)outDst + (size_t)ySlot * pStride;
    ushort* baseU = (ushort*)outDst + (size_t)ySlot * pStride;
    #pragma unroll
    for (int mt = 0; mt < MT; ++mt) {
        #pragma unroll
        for (int nt = 0; nt < NT; ++nt) {
            int y = y0 + py_[nt], x = x0 + px_[nt];
            if (y < H && x < W) {
                #pragma unroll
                for (int r = 0; r < 4; ++r) {
                    int co = co0 + mt * 16 + lg * 4 + r;
                    if (co < Cout) {
                        size_t o = ((size_t)(b * Cout + co)) * HW + (size_t)y * W + x;
                        if (OUTMODE == 0) baseF[o] = acc[mt][nt][r];
                        else              baseU[o] = f2bf(acc[mt][nt][r]);
                    }
                }
            }
        }
    }
}

// ---------------------------------------------------------------------------
// conv_dual: main conv (path 1, blockIdx.y < YSPLIT1) and residual 1x1 conv
// (path 2) co-scheduled in ONE launch for co-residency / stall interleaving.
// ---------------------------------------------------------------------------
template<int TY, int TX, int NSPLIT, int MSPLIT, int MT,
         int K1, int OUT1, int K2, int OUT2>
__global__ __launch_bounds__(256)
void conv_dual(const float* __restrict__ in1, int C1,
               const ushort* __restrict__ in2, int C2, int Cin1,
               const ushort* __restrict__ wt1, void* __restrict__ out1,
               size_t ps1, int CoutPad1, int CinPad1, int nch1, int cps1, int ysplit1,
               const ushort* __restrict__ wt2, void* __restrict__ out2,
               size_t ps2, int CoutPad2, int CinPad2, int nch2, int cps2,
               int H, int W, int Cout, int tilesX, int tilesY) {
    constexpr int LDSU = imax(ldsElems(K1, TY, TX), ldsElems(K2, TY, TX));
    __shared__ ushort sT[LDSU];
    if ((int)blockIdx.y < ysplit1) {
        conv_body<K1, TY, TX, NSPLIT, MSPLIT, MT, OUT1>(
            sT, in1, C1, in2, C2, Cin1, wt1, out1, ps1, blockIdx.y,
            H, W, Cout, CoutPad1, CinPad1, tilesX, tilesY, nch1, cps1);
    } else {
        conv_body<K2, TY, TX, NSPLIT, MSPLIT, MT, OUT2>(
            sT, in1, C1, nullptr, 0, C1, wt2, out2, ps2, blockIdx.y - ysplit1,
            H, W, Cout, CoutPad2, CinPad2, tilesX, tilesY, nch2, cps2);
    }
}

// ---------------------------------------------------------------------------
// conv_mfma5 — stage-32 only (W=30 not %4; tiny stage, atomics fine).
// ---------------------------------------------------------------------------
template<int K, int TY, int TX, int NSPLIT, int MSPLIT, int MT>
__global__ __launch_bounds__(256)
void conv_mfma5(const float* __restrict__ in1, int C1, int Cin,
                const ushort* __restrict__ wt,
                float* __restrict__ outDst,
                int H, int W, int Cout, int CoutPad, int Cin_pad,
                int tilesX, int nchunks, int cps) {
    constexpr int P = K / 2;
    constexpr int XOFF = 4;
    constexpr int JOFF = XOFF - P;
    constexpr int HXs = (TX + K - 1 + JOFF + 3) & ~3;
    constexpr int HY = TY + K - 1;
    constexpr int PITCH = 40;
    constexpr int KK = K * K;
    constexpr int PXW = TY * TX / NSPLIT;
    constexpr int NT = PXW / 16;
    constexpr int G = HXs / 4;
    constexpr int NITEM = 16 * HY * G;

    __shared__ ushort sT[HY * HXs * PITCH];

    const int tid = threadIdx.x;
    const int lane = tid & 63, wv = tid >> 6;
    const int nwave = wv % NSPLIT, mwave = wv / NSPLIT;
    const int l15 = lane & 15, lg = lane >> 4;

    const int txi = blockIdx.x % tilesX;
    const int tyi = blockIdx.x / tilesX;
    const int b = blockIdx.z;
    const int x0 = txi * TX, y0 = tyi * TY;
    const size_t HW = (size_t)H * W;
    const int co0 = mwave * (MT * 16);

    int posBase[NT], py_[NT], px_[NT];
    #pragma unroll
    for (int nt = 0; nt < NT; ++nt) {
        int pidx = nwave * PXW + nt * 16 + l15;
        int py = pidx / TX, px = pidx % TX;
        py_[nt] = py; px_[nt] = px;
        posBase[nt] = (py * HXs + px + JOFF) * PITCH + lg * 8;
    }
    const int aoff = l15 * Cin_pad + lg * 8;

    f32x4 acc[MT][NT];
    #pragma unroll
    for (int i = 0; i < MT; ++i)
        #pragma unroll
        for (int j = 0; j < NT; ++j) acc[i][j] = (f32x4)0.f;

    const int c0 = blockIdx.y * cps;
    const int c1 = (c0 + cps < nchunks) ? c0 + cps : nchunks;

    for (int c = c0; c < c1; ++c) {
        const int ci0 = c * 32;
        __syncthreads();
        for (int i = tid; i < NITEM; i += 256) {
            int g  = i % G;
            int rr = (i / G) % HY;
            int cp = i / (G * HY);
            int ci = ci0 + cp * 2;
            int y  = y0 - P + rr;
            int xg = x0 - XOFF + g * 4;
            ushort* dp = &sT[(rr * HXs + g * 4) * PITCH + cp * 2];
            const float* p0 = in1 + (long long)(b * C1 + ci) * (long long)HW + (long long)y * W + xg;
            bool yok = (unsigned)y < (unsigned)H;
            #pragma unroll
            for (int u = 0; u < 4; ++u) {
                int x = xg + u;
                unsigned pk = 0;
                if (yok && (unsigned)x < (unsigned)W)
                    pk = (unsigned)f2bf(p0[u]) | ((unsigned)f2bf(p0[u + (long long)HW]) << 16);
                *(unsigned*)(dp + u * PITCH) = pk;
            }
        }
        __syncthreads();

        bf16x8 afA[MT];
        {
            const ushort* ap = wt + (size_t)co0 * Cin_pad + ci0 + aoff;
            #pragma unroll
            for (int mt = 0; mt < MT; ++mt)
                afA[mt] = *(const bf16x8*)(ap + (size_t)mt * 16 * Cin_pad);
        }
        #pragma unroll
        for (int t = 0; t < KK; ++t) {
            bf16x8 afB[MT];
            if (t + 1 < KK) {
                const ushort* ap = wt + (size_t)((t + 1) * CoutPad + co0) * Cin_pad + ci0 + aoff;
                #pragma unroll
                for (int mt = 0; mt < MT; ++mt)
                    afB[mt] = *(const bf16x8*)(ap + (size_t)mt * 16 * Cin_pad);
            }
            const int tOff = ((t / K) * HXs + (t % K)) * PITCH;
            bf16x8 bf[NT];
            #pragma unroll
            for (int nt = 0; nt < NT; ++nt)
                bf[nt] = *(const bf16x8*)(sT + posBase[nt] + tOff);
            #pragma unroll
            for (int mt = 0; mt < MT; ++mt)
                #pragma unroll
                for (int nt = 0; nt < NT; ++nt)
                    acc[mt][nt] = __builtin_amdgcn_mfma_f32_16x16x32_bf16(
                        afA[mt], bf[nt], acc[mt][nt], 0, 0, 0);
            if (t + 1 < KK) {
                #pragma unroll
                for (int mt = 0; mt < MT; ++mt) afA[mt] = afB[mt];
            }
        }
    }

    #pragma unroll
    for (int mt = 0; mt < MT; ++mt) {
        #pragma unroll
        for (int nt = 0; nt < NT; ++nt) {
            int y = y0 + py_[nt], x = x0 + px_[nt];
            if (y < H && x < W) {
                #pragma unroll
                for (int r = 0; r < 4; ++r) {
                    int co = co0 + mt * 16 + lg * 4 + r;
                    if (co < Cout) {
                        size_t o = ((size_t)(b * Cout + co)) * HW + (size_t)y * W + x;
                        unsafeAtomicAdd(&outDst[o], acc[mt][nt][r]);
                    }
                }
            }
        }
    }
}

// ---------------------------------------------------------------------------
// ConvTranspose2d k3/s2/p1/op1 via MFMA, 4-phase subpixel decomposition.
// ---------------------------------------------------------------------------
template<int TY, int TX, int NSPLIT, int MT>
__global__ __launch_bounds__(256)
void convt_mfma(const float* __restrict__ in,
                const ushort* __restrict__ wtp,
                ushort* __restrict__ out,
                int Cin, int Cout, int Cin_pad, int Hin, int Win,
                int tilesX, int tilesY) {
    constexpr int HY = TY + 1, HX = TX + 1;
    constexpr int PITCH = 40;
    constexpr int NPX = TY * TX;
    constexpr int PXW = NPX / NSPLIT;
    constexpr int NT = PXW / 16;
    constexpr int NPOS = HY * HX;
    constexpr int NIT = (NPOS * 16 + 63) & ~63;

    __shared__ ushort sT[NPOS * PITCH];

    constexpr int toy[9] = {0, 0, 0, 1, 0, 1, 1, 0, 0};
    constexpr int tox[9] = {0, 1, 0, 0, 0, 1, 0, 1, 0};
    constexpr int tph[9] = {0, 1, 1, 2, 2, 3, 3, 3, 3};

    const int tid = threadIdx.x;
    const int lane = tid & 63, wv = tid >> 6;
    const int nwave = wv % NSPLIT, mwave = wv / NSPLIT;
    const int l15 = lane & 15, lg = lane >> 4;

    int tile = blockIdx.x;
    const int txi = tile % tilesX;
    int rem = tile / tilesX;
    const int tyi = rem % tilesY;
    const int b = rem / tilesY;
    const int x0 = txi * TX, y0 = tyi * TY;
    const size_t HWi = (size_t)Hin * Win;
    const int Wo = 2 * Win;
    const size_t HWo = (size_t)4 * HWi;

    const int co0 = mwave * (MT * 16);

    int posBase[NT], py_[NT], px_[NT];
    #pragma unroll
    for (int nt = 0; nt < NT; ++nt) {
        int pidx = nwave * PXW + nt * 16 + l15;
        int py = pidx / TX, px = pidx % TX;
        py_[nt] = py; px_[nt] = px;
        posBase[nt] = (py * HX + px) * PITCH + lg * 8;
    }
    const int aoff = l15 * Cin_pad + lg * 8;

    f32x4 acc[4][MT][NT];
    #pragma unroll
    for (int p = 0; p < 4; ++p)
        #pragma unroll
        for (int i = 0; i < MT; ++i)
            #pragma unroll
            for (int j = 0; j < NT; ++j) acc[p][i][j] = (f32x4)0.f;

    const int nchunks = Cin_pad / 32;
    for (int c = 0; c < nchunks; ++c) {
        const int ci0 = c * 32;
        __syncthreads();
        for (int i = tid; i < NIT; i += 256) {
            int cp = (i >> 2) & 15;
            int pos = (i & 3) | ((i >> 6) << 2);
            if (pos < NPOS) {
                int hy = pos / HX, hx = pos % HX;
                int y = y0 + hy, x = x0 + hx;
                int ci = ci0 + cp * 2;
                unsigned pk = 0;
                if ((unsigned)y < (unsigned)Hin && (unsigned)x < (unsigned)Win && ci < Cin) {
                    const float* p0 = in + (size_t)(b * Cin + ci) * HWi + (size_t)y * Win + x;
                    float v0 = p0[0];
                    float v1 = (ci + 1 < Cin) ? p0[HWi] : 0.f;
                    pk = pack2bf(v0, v1);
                }
                *(unsigned*)&sT[pos * PITCH + cp * 2] = pk;
            }
        }
        __syncthreads();

        bf16x8 afA[MT];
        {
            const ushort* ap = wtp + (size_t)co0 * Cin_pad + ci0 + aoff;
            #pragma unroll
            for (int mt = 0; mt < MT; ++mt)
                afA[mt] = *(const bf16x8*)(ap + (size_t)mt * 16 * Cin_pad);
        }
        #pragma unroll
        for (int t = 0; t < 9; ++t) {
            bf16x8 afB[MT];
            if (t + 1 < 9) {
                const ushort* ap = wtp + (size_t)((t + 1) * Cout + co0) * Cin_pad + ci0 + aoff;
                #pragma unroll
                for (int mt = 0; mt < MT; ++mt)
                    afB[mt] = *(const bf16x8*)(ap + (size_t)mt * 16 * Cin_pad);
            }
            const int tOff = (toy[t] * HX + tox[t]) * PITCH;
            bf16x8 bf[NT];
            #pragma unroll
            for (int nt = 0; nt < NT; ++nt)
                bf[nt] = *(const bf16x8*)(sT + posBase[nt] + tOff);
            #pragma unroll
            for (int mt = 0; mt < MT; ++mt)
                #pragma unroll
                for (int nt = 0; nt < NT; ++nt)
                    acc[tph[t]][mt][nt] = __builtin_amdgcn_mfma_f32_16x16x32_bf16(
                        afA[mt], bf[nt], acc[tph[t]][mt][nt], 0, 0, 0);
            if (t + 1 < 9) {
                #pragma unroll
                for (int mt = 0; mt < MT; ++mt) afA[mt] = afB[mt];
            }
        }
    }

    #pragma unroll
    for (int dy = 0; dy < 2; ++dy) {
        #pragma unroll
        for (int mt = 0; mt < MT; ++mt) {
            #pragma unroll
            for (int nt = 0; nt < NT; ++nt) {
                int y = y0 + py_[nt], x = x0 + px_[nt];
                if (y < Hin && x < Win) {
                    #pragma unroll
                    for (int r = 0; r < 4; ++r) {
                        int co = co0 + mt * 16 + lg * 4 + r;
                        unsigned pk = pack2bf(acc[dy * 2][mt][nt][r], acc[dy * 2 + 1][mt][nt][r]);
                        *(unsigned*)&out[((size_t)(b * Cout + co)) * HWo + (size_t)(2 * y + dy) * Wo + 2 * x] = pk;
                    }
                }
            }
        }
    }
}

// ---------------------------------------------------------------------------
// InstanceNorm stats over NS fp32 partial planes.
// ---------------------------------------------------------------------------
__global__ __launch_bounds__(256)
void inorm_stats2(const float* __restrict__ x, size_t pStride, int NS,
                  float* __restrict__ mean, float* __restrict__ istd, int HW) {
    int bc = blockIdx.x;
    const float4* p = (const float4*)(x + (size_t)bc * HW);
    size_t st4 = pStride >> 2;
    int n4 = HW >> 2;
    float s = 0.f, ss = 0.f;
    for (int i = threadIdx.x; i < n4; i += 256) {
        float4 v = p[i];
        for (int sp = 1; sp < NS; ++sp) {
            float4 w = p[i + sp * st4];
            v.x += w.x; v.y += w.y; v.z += w.z; v.w += w.w;
        }
        s += v.x + v.y + v.z + v.w;
        ss += v.x * v.x + v.y * v.y + v.z * v.z + v.w * v.w;
    }
    #pragma unroll
    for (int o = 32; o > 0; o >>= 1) {
        s  += __shfl_down(s, o);
        ss += __shfl_down(ss, o);
    }
    __shared__ float sh[4][2];
    int wid = threadIdx.x >> 6, ln = threadIdx.x & 63;
    if (ln == 0) { sh[wid][0] = s; sh[wid][1] = ss; }
    __syncthreads();
    if (threadIdx.x == 0) {
        float S = 0.f, SS = 0.f;
        for (int i = 0; i < 4; ++i) { S += sh[i][0]; SS += sh[i][1]; }
        float m = S / HW;
        float v = SS / HW - m * m;
        v = v > 0.f ? v : 0.f;
        mean[bc] = m;
        istd[bc] = rsqrtf(v + 1e-5f);
    }
}

// ---------------------------------------------------------------------------
// Epilogue over fp32 partial planes: feat = relu((Σraw - m)*istd) [+ Σres + br]
// RESMODE: 0 none, 1 fp32 res planes, 2 bf16 res single plane.
// ---------------------------------------------------------------------------
template<int RESMODE>
__global__ __launch_bounds__(256)
void epilogue2(const float* __restrict__ raw, size_t rawStride, int NS,
               const float* __restrict__ mean,
               const float* __restrict__ istd,
               const void* __restrict__ res, size_t resStride, int NSR,
               const float* __restrict__ br,
               float* __restrict__ feat,
               int HW, int Cout, int total4) {
    int i = blockIdx.x * 256 + threadIdx.x;
    if (i >= total4) return;
    int bc = (int)(((long long)i * 4) / HW);
    float m = mean[bc], is = istd[bc];
    size_t rs4 = rawStride >> 2;
    float4 r = ((const float4*)raw)[i];
    for (int sp = 1; sp < NS; ++sp) {
        float4 w = ((const float4*)raw)[i + sp * rs4];
        r.x += w.x; r.y += w.y; r.z += w.z; r.w += w.w;
    }
    float4 o;
    o.x = fmaxf((r.x - m) * is, 0.f);
    o.y = fmaxf((r.y - m) * is, 0.f);
    o.z = fmaxf((r.z - m) * is, 0.f);
    o.w = fmaxf((r.w - m) * is, 0.f);
    if (RESMODE == 1) {
        float bb = br[bc % Cout];
        size_t es4 = resStride >> 2;
        float4 e = ((const float4*)res)[i];
        for (int sp = 1; sp < NSR; ++sp) {
            float4 w = ((const float4*)res)[i + sp * es4];
            e.x += w.x; e.y += w.y; e.z += w.z; e.w += w.w;
        }
        o.x += e.x + bb; o.y += e.y + bb; o.z += e.z + bb; o.w += e.w + bb;
    } else if (RESMODE == 2) {
        float bb = br[bc % Cout];
        ushort4 e = ((const ushort4*)res)[i];
        o.x += bf2f(e.x) + bb; o.y += bf2f(e.y) + bb;
        o.z += bf2f(e.z) + bb; o.w += bf2f(e.w) + bb;
    }
    ((float4*)feat)[i] = o;
}

extern "C" void kernel_launch(void* const* d_in, const int* in_sizes, int n_in,
                              void* d_out, int out_size, void* d_ws, size_t ws_size,
                              hipStream_t stream) {
    const float* f4   = (const float*)d_in[0];
    const float* f8   = (const float*)d_in[1];
    const float* f16  = (const float*)d_in[2];
    const float* f32  = (const float*)d_in[3];
    const float* w32  = (const float*)d_in[4];
    const float* wt32 = (const float*)d_in[6];
    const float* w16  = (const float*)d_in[7];
    const float* wr16 = (const float*)d_in[9];
    const float* br16 = (const float*)d_in[10];
    const float* wt16 = (const float*)d_in[11];
    const float* w8   = (const float*)d_in[12];
    const float* wr8  = (const float*)d_in[14];
    const float* br8  = (const float*)d_in[15];
    const float* wt8  = (const float*)d_in[16];
    const float* w4   = (const float*)d_in[17];
    const float* wr4  = (const float*)d_in[19];
    const float* br4  = (const float*)d_in[20];
    // main-conv biases cancel under InstanceNorm -> unused.

    float* out = (float*)d_out;

    const int B = 2, C = 256;
    const int H4 = 160, W4 = 240;
    const int H8 = 80,  W8 = 120;
    const int H16 = 40, W16 = 60;
    const int H32 = 20, W32 = 30;

    float* feat4  = out;
    float* feat8  = out + (size_t)B * 48 * H4 * W4;
    float* feat16 = feat8 + (size_t)B * 64 * H8 * W8;
    float* feat32 = feat16 + (size_t)B * 192 * H16 * W16;

    const size_t bufElems = (size_t)B * 48 * H4 * W4;  // 3,686,400
    ushort* wsUpB  = (ushort*)d_ws;
    float*  wsRawP = (float*)(wsUpB + bufElems);
    ushort* wsResB = (ushort*)(wsRawP + bufElems);
    float*  stMean = (float*)(wsResB + bufElems);
    float*  stIstd = stMean + 512;
    float*  wsResF = (float*)wsResB;

    // bf16 repacked weights in the feat4 output region (written last).
    ushort* wb = (ushort*)feat4;
    ushort* W32p = wb;                          // 9*192*256
    ushort* W16p = W32p + 9 * 192 * 256;        // 25*192*448
    ushort* W8p  = W16p + 25 * 192 * 448;       // 25*64*320
    ushort* W4p  = W8p  + 25 * 64 * 320;        // 25*64*320 (Cout pad 48->64)
    ushort* R16p = W4p  + 25 * 64 * 320;        // 192*256
    ushort* R8p  = R16p + 192 * 256;            // 64*256
    ushort* R4p  = R8p  + 64 * 256;             // 64*256 (pad)
    ushort* T32p = R4p  + 64 * 256;             // 9*192*160
    ushort* T16p = T32p + 9 * 192 * 160;        // 9*64*192
    ushort* T8p  = T16p + 9 * 64 * 192;         // 9*48*64

    // ---- weight repacks ----
    {
        int t1 = 9 * 192 * 256;
        transpose_w<<<cdiv(t1, 256), 256, 0, stream>>>(w32, W32p, 160, 192, 256, 256, 9, t1);
        int t2 = 25 * 192 * 448;
        transpose_w<<<cdiv(t2, 256), 256, 0, stream>>>(w16, W16p, 192, 192, 448, 448, 25, t2);
        int t3 = 25 * 64 * 320;
        transpose_w<<<cdiv(t3, 256), 256, 0, stream>>>(w8, W8p, 64, 64, 320, 320, 25, t3);
        int t4 = 25 * 64 * 320;
        transpose_w<<<cdiv(t4, 256), 256, 0, stream>>>(w4, W4p, 48, 64, 304, 320, 25, t4);
        int t5 = 192 * 256;
        transpose_w<<<cdiv(t5, 256), 256, 0, stream>>>(wr16, R16p, 192, 192, 256, 256, 1, t5);
        int t6 = 64 * 256;
        transpose_w<<<cdiv(t6, 256), 256, 0, stream>>>(wr8, R8p, 64, 64, 256, 256, 1, t6);
        int t7 = 64 * 256;
        transpose_w<<<cdiv(t7, 256), 256, 0, stream>>>(wr4, R4p, 48, 64, 256, 256, 1, t7);
        int u1 = 9 * 192 * 160;
        transpose_wt<<<cdiv(u1, 256), 256, 0, stream>>>(wt32, T32p, 160, 192, 160, u1);
        int u2 = 9 * 64 * 192;
        transpose_wt<<<cdiv(u2, 256), 256, 0, stream>>>(wt16, T16p, 192, 64, 192, u2);
        int u3 = 9 * 48 * 64;
        transpose_wt<<<cdiv(u3, 256), 256, 0, stream>>>(wt8, T8p, 64, 48, 64, u3);
    }

    // ---------------- stage 32 (K=3, Cin=256, Cout=160, 20x30) ----------------
    {
        hipMemsetAsync(wsRawP, 0, (size_t)B * 160 * H32 * W32 * 4, stream);
        int tX = cdiv(W32, 8), tY = cdiv(H32, 4);   // 4 x 5
        dim3 g(tX * tY, 8, B);
        conv_mfma5<3, 4, 8, 1, 4, 3><<<g, 256, 0, stream>>>(
            f32, C, C, W32p, wsRawP, H32, W32, 160, 192, 256, tX, 8, 1);
        inorm_stats2<<<B * 160, 256, 0, stream>>>(wsRawP, 0, 1, stMean, stIstd, H32 * W32);
        int tot4 = B * 160 * H32 * W32 / 4;
        epilogue2<0><<<cdiv(tot4, 256), 256, 0, stream>>>(
            wsRawP, 0, 1, stMean, stIstd, nullptr, 0, 0, nullptr, feat32, H32 * W32, 160, tot4);
        int uX = cdiv(W32, 8), uY = cdiv(H32, 2);
        convt_mfma<2, 8, 1, 3><<<uX * uY * B, 256, 0, stream>>>(
            feat32, T32p, wsUpB, 160, 192, 160, H32, W32, uX, uY);
    }
    // ---------------- stage 16 (K=5, Cin=256+192, Cout=192, 40x60) ------------
    {
        size_t SZ16 = (size_t)B * 192 * H16 * W16;  // 921,600
        int tX = cdiv(W16, 8), tY = cdiv(H16, 4);   // 8 x 10 = 80 tiles
        dim3 g(tX * tY, 6, B);                       // y 0-3 main, 4-5 res
        conv_dual<4, 8, 1, 4, 3, 5, 0, 1, 0><<<g, 256, 0, stream>>>(
            f16, C, wsUpB, 192, 448,
            W16p, wsRawP, SZ16, 192, 448, 7, 2, 4,
            R16p, wsResF, SZ16, 192, 256, 4, 2,
            H16, W16, 192, tX, tY);
        inorm_stats2<<<B * 192, 256, 0, stream>>>(wsRawP, SZ16, 4, stMean, stIstd, H16 * W16);
        int tot4 = (int)(SZ16 / 4);
        epilogue2<1><<<cdiv(tot4, 256), 256, 0, stream>>>(
            wsRawP, SZ16, 4, stMean, stIstd, wsResF, SZ16, 2, br16, feat16, H16 * W16, 192, tot4);
        int uX = cdiv(W16, 8), uY = cdiv(H16, 4);
        convt_mfma<4, 8, 2, 2><<<uX * uY * B, 256, 0, stream>>>(
            feat16, T16p, wsUpB, 192, 64, 192, H16, W16, uX, uY);
    }
    // ---------------- stage 8 (K=5, Cin=256+64, Cout=64, 80x120) --------------
    {
        size_t SZ8 = (size_t)B * 64 * H8 * W8;      // 1,228,800
        int tX = cdiv(W8, 16), tY = cdiv(H8, 8);    // 8 x 10 = 80 tiles
        dim3 g(tX * tY, 4, B);                       // y 0-2 main, 3 res
        conv_dual<8, 16, 2, 2, 2, 5, 0, 1, 0><<<g, 256, 0, stream>>>(
            f8, C, wsUpB, 64, 320,
            W8p, wsRawP, SZ8, 64, 320, 5, 2, 3,
            R8p, wsResF, SZ8, 64, 256, 4, 4,
            H8, W8, 64, tX, tY);
        inorm_stats2<<<B * 64, 256, 0, stream>>>(wsRawP, SZ8, 3, stMean, stIstd, H8 * W8);
        int tot4 = (int)(SZ8 / 4);
        epilogue2<1><<<cdiv(tot4, 256), 256, 0, stream>>>(
            wsRawP, SZ8, 3, stMean, stIstd, wsResF, SZ8, 1, br8, feat8, H8 * W8, 64, tot4);
        int uX = cdiv(W8, 16), uY = cdiv(H8, 4);
        convt_mfma<4, 16, 4, 3><<<uX * uY * B, 256, 0, stream>>>(
            feat8, T8p, wsUpB, 64, 48, 64, H8, W8, uX, uY);
    }
    // ---------------- stage 4 (K=5, Cin=256+48, Cout=48->64pad, 160x240) ------
    {
        size_t SZ4 = (size_t)B * 48 * H4 * W4;      // 3,686,400
        int tX = cdiv(W4, 16), tY = cdiv(H4, 8);    // 15 x 20 = 300 tiles
        dim3 g(tX * tY, 2, B);                       // y 0 main, 1 res
        conv_dual<8, 16, 2, 2, 2, 5, 0, 1, 2><<<g, 256, 0, stream>>>(
            f4, C, wsUpB, 48, 304,
            W4p, wsRawP, SZ4, 64, 320, 5, 5, 1,
            R4p, wsResB, 0, 64, 256, 4, 4,
            H4, W4, 48, tX, tY);
        inorm_stats2<<<B * 48, 256, 0, stream>>>(wsRawP, 0, 1, stMean, stIstd, H4 * W4);
        int tot4 = (int)(SZ4 / 4);
        epilogue2<2><<<cdiv(tot4, 256), 256, 0, stream>>>(
            wsRawP, 0, 1, stMean, stIstd, wsResB, 0, 0, br4, feat4, H4 * W4, 48, tot4);
    }
}

// Round 16
// 566.214 us; speedup vs baseline: 1.2272x; 1.0004x over previous
//
#include <hip/hip_runtime.h>
#include <hip/hip_bf16.h>

typedef __attribute__((ext_vector_type(8))) short bf16x8;
typedef __attribute__((ext_vector_type(4))) float f32x4;

static inline int cdiv(int a, int b) { return (a + b - 1) / b; }

__device__ __forceinline__ ushort f2bf(float f) {
    unsigned u = __float_as_uint(f);
    unsigned r = (u + 0x7FFFu + ((u >> 16) & 1u)) >> 16;
    return (ushort)r;
}
__device__ __forceinline__ unsigned pack2bf(float lo, float hi) {
    unsigned r;
    asm("v_cvt_pk_bf16_f32 %0, %1, %2" : "=v"(r) : "v"(lo), "v"(hi));
    return r;
}
__device__ __forceinline__ float bf2f(ushort u) {
    return __uint_as_float((unsigned)u << 16);
}

constexpr int ldsElems(int K, int TY, int TX, int PITCH) {
    int P = K / 2;
    int XOFF = (K == 1) ? 0 : 4;
    int JOFF = XOFF - P;
    int HXs = (TX + K - 1 + JOFF + 3) & ~3;
    int HY = TY + K - 1;
    return HY * HXs * PITCH;
}
constexpr int imax(int a, int b) { return a > b ? a : b; }

// ---------------------------------------------------------------------------
// Weight repack: w[co][ci][t] (fp32) -> wt[t][co_pad][ci_pad] (bf16), zero-pad.
// ---------------------------------------------------------------------------
__global__ __launch_bounds__(256)
void transpose_w(const float* __restrict__ w, ushort* __restrict__ wt,
                 int Cout, int CoutPad, int Cin, int Cin_pad, int KK, int total) {
    int idx = blockIdx.x * 256 + threadIdx.x;
    if (idx >= total) return;
    int ci = idx % Cin_pad;
    int rem = idx / Cin_pad;
    int co = rem % CoutPad;
    int t  = rem / CoutPad;
    float v = (ci < Cin && co < Cout) ? w[((size_t)co * Cin + ci) * KK + t] : 0.f;
    wt[idx] = f2bf(v);
}

// ---------------------------------------------------------------------------
// ConvTranspose weight repack: torch wt[ci][co][ky][kx] -> wtp[t][co][ci_pad]
// ---------------------------------------------------------------------------
__device__ const int g_tky[9] = {1, 1, 1, 0, 2, 0, 0, 2, 2};
__device__ const int g_tkx[9] = {1, 0, 2, 1, 1, 0, 2, 0, 2};

__global__ __launch_bounds__(256)
void transpose_wt(const float* __restrict__ wt, ushort* __restrict__ dst,
                  int Cin, int Cout, int Cin_pad, int total) {
    int idx = blockIdx.x * 256 + threadIdx.x;
    if (idx >= total) return;
    int ci = idx % Cin_pad;
    int rem = idx / Cin_pad;
    int co = rem % Cout;
    int t  = rem / Cout;
    float v = 0.f;
    if (ci < Cin)
        v = wt[((size_t)(ci * Cout + co) * 3 + g_tky[t]) * 3 + g_tkx[t]];
    dst[idx] = f2bf(v);
}

// ---------------------------------------------------------------------------
// conv_body: proven implicit-GEMM conv structure as a device function.
//  - C64: 64-ci chunks (PITCH=72) halving barriers (grid-capped stages), or
//    32-ci chunks (PITCH=40) halving LDS -> 2x co-residency (LDS-capped).
//  - depth-4 weight ring over KS*K*K virtual taps, JIT B ds_reads,
//    g-fastest coalesced staging, rotated LDS writes, XCD swizzle,
//    partial-plane split-K (ySlot). OUTMODE: 0 fp32 plane, 2 bf16 plane.
// ---------------------------------------------------------------------------
template<int K, int TY, int TX, int NSPLIT, int MSPLIT, int MT, int OUTMODE, bool C64>
__device__ __forceinline__
void conv_body(ushort* sT,
               const float* __restrict__ in1, int C1,
               const ushort* __restrict__ in2, int C2, int Cin,
               const ushort* __restrict__ wt,
               void* __restrict__ outDst, size_t pStride, int ySlot,
               int H, int W, int Cout, int CoutPad, int Cin_pad,
               int tilesX, int tilesY, int nchunks, int cps) {
    constexpr int P = K / 2;
    constexpr int XOFF = (K == 1) ? 0 : 4;
    constexpr int JOFF = XOFF - P;
    constexpr int HXs = (TX + K - 1 + JOFF + 3) & ~3;
    constexpr int HY = TY + K - 1;
    constexpr int CHUNK = C64 ? 64 : 32;
    constexpr int PITCH = C64 ? 72 : 40;
    constexpr int KS = C64 ? 2 : 1;
    constexpr int KK = K * K;
    constexpr int NVT = KS * KK;
    constexpr int PXW = TY * TX / NSPLIT;
    constexpr int NT = PXW / 16;
    constexpr int G = HXs / 4;
    constexpr int NITEM = (CHUNK / 2) * HY * G;

    const int tid = threadIdx.x;
    const int lane = tid & 63, wv = tid >> 6;
    const int nwave = wv % NSPLIT, mwave = wv / NSPLIT;
    const int l15 = lane & 15, lg = lane >> 4;

    // XCD-bijective swizzle, tiles column-major (y fastest)
    const int nwg = tilesX * tilesY;
    int bid = blockIdx.x;
    int q8 = nwg >> 3, r8 = nwg & 7;
    int xcd = bid & 7, sidx = bid >> 3;
    int wg = (xcd < r8 ? xcd * (q8 + 1) : r8 * (q8 + 1) + (xcd - r8) * q8) + sidx;
    const int txi = wg / tilesY;
    const int tyi = wg % tilesY;

    const int b = blockIdx.z;
    const int x0 = txi * TX, y0 = tyi * TY;
    const size_t HW = (size_t)H * W;

    const int co0 = mwave * (MT * 16);

    int posBase[NT], py_[NT], px_[NT];
    #pragma unroll
    for (int nt = 0; nt < NT; ++nt) {
        int pidx = nwave * PXW + nt * 16 + l15;
        int py = pidx / TX, px = pidx % TX;
        py_[nt] = py; px_[nt] = px;
        posBase[nt] = (py * HXs + px + JOFF) * PITCH + lg * 8;
    }
    const int aoff = l15 * Cin_pad + lg * 8;

    f32x4 acc[MT][NT];
    #pragma unroll
    for (int i = 0; i < MT; ++i)
        #pragma unroll
        for (int j = 0; j < NT; ++j) acc[i][j] = (f32x4)0.f;

    const int c0 = ySlot * cps;
    const int c1 = (c0 + cps < nchunks) ? c0 + cps : nchunks;

    for (int c = c0; c < c1; ++c) {
        const int ci0 = c * CHUNK;
        __syncthreads();
        // ---- stage halo tile ----
        #pragma unroll 3
        for (int i = tid; i < NITEM; i += 256) {
            int g  = i % G;
            int rr = (i / G) % HY;
            int cp = i / (G * HY);
            int ci = ci0 + cp * 2;
            int y  = y0 - P + rr;
            int xg = x0 - XOFF + g * 4;
            ushort* dp = &sT[(rr * HXs + g * 4) * PITCH + cp * 2];
            bool yok = (unsigned)y < (unsigned)H;
            unsigned d0, d1, d2, d3;
            if (ci < C1) {
                const float* p0 = in1 + (long long)(b * C1 + ci) * (long long)HW + (long long)y * W + xg;
                if (yok && xg >= 0 && (xg + 3) < W) {
                    float4 a  = *(const float4*)p0;
                    float4 b2 = *(const float4*)(p0 + HW);
                    d0 = pack2bf(a.x, b2.x);
                    d1 = pack2bf(a.y, b2.y);
                    d2 = pack2bf(a.z, b2.z);
                    d3 = pack2bf(a.w, b2.w);
                } else {
                    unsigned t0 = 0, t1 = 0, t2 = 0, t3 = 0;
                    #pragma unroll
                    for (int u = 0; u < 4; ++u) {
                        int x = xg + u;
                        unsigned pk = 0;
                        if (yok && (unsigned)x < (unsigned)W)
                            pk = (unsigned)f2bf(p0[u]) | ((unsigned)f2bf(p0[u + (long long)HW]) << 16);
                        if (u == 0) t0 = pk; else if (u == 1) t1 = pk;
                        else if (u == 2) t2 = pk; else t3 = pk;
                    }
                    d0 = t0; d1 = t1; d2 = t2; d3 = t3;
                }
            } else {
                const ushort* q0 = in2 + (long long)(b * C2 + (ci - C1)) * (long long)HW + (long long)y * W + xg;
                if (yok && xg >= 0 && (xg + 3) < W && (ci + 1) < Cin) {
                    ushort4 a  = *(const ushort4*)q0;
                    ushort4 b2 = *(const ushort4*)(q0 + HW);
                    d0 = (unsigned)a.x | ((unsigned)b2.x << 16);
                    d1 = (unsigned)a.y | ((unsigned)b2.y << 16);
                    d2 = (unsigned)a.z | ((unsigned)b2.z << 16);
                    d3 = (unsigned)a.w | ((unsigned)b2.w << 16);
                } else {
                    unsigned t0 = 0, t1 = 0, t2 = 0, t3 = 0;
                    #pragma unroll
                    for (int u = 0; u < 4; ++u) {
                        int x = xg + u;
                        unsigned pk = 0;
                        if (yok && (unsigned)x < (unsigned)W && ci < Cin) {
                            unsigned v0 = q0[u];
                            unsigned v1 = (ci + 1 < Cin) ? q0[u + (long long)HW] : 0u;
                            pk = v0 | (v1 << 16);
                        }
                        if (u == 0) t0 = pk; else if (u == 1) t1 = pk;
                        else if (u == 2) t2 = pk; else t3 = pk;
                    }
                    d0 = t0; d1 = t1; d2 = t2; d3 = t3;
                }
            }
            int s = (g + rr) & 3;
            #pragma unroll
            for (int u = 0; u < 4; ++u) {
                int cc2 = (u + s) & 3;
                unsigned val = (cc2 & 2) ? ((cc2 & 1) ? d3 : d2)
                                         : ((cc2 & 1) ? d1 : d0);
                *(unsigned*)(dp + cc2 * PITCH) = val;
            }
        }
        __syncthreads();

        // ---- depth-4 weight ring over NVT virtual taps ----
        bf16x8 af[4][MT];
        #pragma unroll
        for (int s = 0; s < 3; ++s) {
            if (s < NVT) {
                const int t = s / KS, ks = s % KS;
                const ushort* ap = wt + (size_t)((size_t)t * CoutPad + co0) * Cin_pad
                                      + ci0 + ks * 32 + aoff;
                #pragma unroll
                for (int mt = 0; mt < MT; ++mt)
                    af[s][mt] = *(const bf16x8*)(ap + (size_t)mt * 16 * Cin_pad);
            }
        }
        #pragma unroll
        for (int tt = 0; tt < NVT; ++tt) {
            if (tt + 3 < NVT) {
                const int tn = (tt + 3) / KS, ksn = (tt + 3) % KS;
                const ushort* ap = wt + (size_t)((size_t)tn * CoutPad + co0) * Cin_pad
                                      + ci0 + ksn * 32 + aoff;
                #pragma unroll
                for (int mt = 0; mt < MT; ++mt)
                    af[(tt + 3) & 3][mt] = *(const bf16x8*)(ap + (size_t)mt * 16 * Cin_pad);
            }
            const int t = tt / KS, ks = tt % KS;
            const int tOff = ((t / K) * HXs + (t % K)) * PITCH + ks * 32;
            bf16x8 bf[NT];
            #pragma unroll
            for (int nt = 0; nt < NT; ++nt)
                bf[nt] = *(const bf16x8*)(sT + posBase[nt] + tOff);
            #pragma unroll
            for (int mt = 0; mt < MT; ++mt)
                #pragma unroll
                for (int nt = 0; nt < NT; ++nt)
                    acc[mt][nt] = __builtin_amdgcn_mfma_f32_16x16x32_bf16(
                        af[tt & 3][mt], bf[nt], acc[mt][nt], 0, 0, 0);
        }
    }

    // ---- store partial plane ----
    float*  baseF = (float*)outDst + (size_t)ySlot * pStride;
    ushort* baseU = (ushort*)outDst + (size_t)ySlot * pStride;
    #pragma unroll
    for (int mt = 0; mt < MT; ++mt) {
        #pragma unroll
        for (int nt = 0; nt < NT; ++nt) {
            int y = y0 + py_[nt], x = x0 + px_[nt];
            if (y < H && x < W) {
                #pragma unroll
                for (int r = 0; r < 4; ++r) {
                    int co = co0 + mt * 16 + lg * 4 + r;
                    if (co < Cout) {
                        size_t o = ((size_t)(b * Cout + co)) * HW + (size_t)y * W + x;
                        if (OUTMODE == 0) baseF[o] = acc[mt][nt][r];
                        else              baseU[o] = f2bf(acc[mt][nt][r]);
                    }
                }
            }
        }
    }
}

// ---------------------------------------------------------------------------
// conv_dual: main conv (blockIdx.y < ysplit1) and residual 1x1 conv co-launched.
// ---------------------------------------------------------------------------
template<int TY, int TX, int NSPLIT, int MSPLIT, int MT,
         int K1, int OUT1, int K2, int OUT2, bool C64>
__global__ __launch_bounds__(256)
void conv_dual(const float* __restrict__ in1, int C1,
               const ushort* __restrict__ in2, int C2, int Cin1,
               const ushort* __restrict__ wt1, void* __restrict__ out1,
               size_t ps1, int CoutPad1, int CinPad1, int nch1, int cps1, int ysplit1,
               const ushort* __restrict__ wt2, void* __restrict__ out2,
               size_t ps2, int CoutPad2, int CinPad2, int nch2, int cps2,
               int H, int W, int Cout, int tilesX, int tilesY) {
    constexpr int PITCH = C64 ? 72 : 40;
    constexpr int LDSU = imax(ldsElems(K1, TY, TX, PITCH), ldsElems(K2, TY, TX, PITCH));
    __shared__ ushort sT[LDSU];
    if ((int)blockIdx.y < ysplit1) {
        conv_body<K1, TY, TX, NSPLIT, MSPLIT, MT, OUT1, C64>(
            sT, in1, C1, in2, C2, Cin1, wt1, out1, ps1, blockIdx.y,
            H, W, Cout, CoutPad1, CinPad1, tilesX, tilesY, nch1, cps1);
    } else {
        conv_body<K2, TY, TX, NSPLIT, MSPLIT, MT, OUT2, C64>(
            sT, in1, C1, nullptr, 0, C1, wt2, out2, ps2, blockIdx.y - ysplit1,
            H, W, Cout, CoutPad2, CinPad2, tilesX, tilesY, nch2, cps2);
    }
}

// ---------------------------------------------------------------------------
// conv_mfma5 — stage-32 only (W=30 not %4; tiny stage, atomics fine).
// ---------------------------------------------------------------------------
template<int K, int TY, int TX, int NSPLIT, int MSPLIT, int MT>
__global__ __launch_bounds__(256)
void conv_mfma5(const float* __restrict__ in1, int C1, int Cin,
                const ushort* __restrict__ wt,
                float* __restrict__ outDst,
                int H, int W, int Cout, int CoutPad, int Cin_pad,
                int tilesX, int nchunks, int cps) {
    constexpr int P = K / 2;
    constexpr int XOFF = 4;
    constexpr int JOFF = XOFF - P;
    constexpr int HXs = (TX + K - 1 + JOFF + 3) & ~3;
    constexpr int HY = TY + K - 1;
    constexpr int PITCH = 40;
    constexpr int KK = K * K;
    constexpr int PXW = TY * TX / NSPLIT;
    constexpr int NT = PXW / 16;
    constexpr int G = HXs / 4;
    constexpr int NITEM = 16 * HY * G;

    __shared__ ushort sT[HY * HXs * PITCH];

    const int tid = threadIdx.x;
    const int lane = tid & 63, wv = tid >> 6;
    const int nwave = wv % NSPLIT, mwave = wv / NSPLIT;
    const int l15 = lane & 15, lg = lane >> 4;

    const int txi = blockIdx.x % tilesX;
    const int tyi = blockIdx.x / tilesX;
    const int b = blockIdx.z;
    const int x0 = txi * TX, y0 = tyi * TY;
    const size_t HW = (size_t)H * W;
    const int co0 = mwave * (MT * 16);

    int posBase[NT], py_[NT], px_[NT];
    #pragma unroll
    for (int nt = 0; nt < NT; ++nt) {
        int pidx = nwave * PXW + nt * 16 + l15;
        int py = pidx / TX, px = pidx % TX;
        py_[nt] = py; px_[nt] = px;
        posBase[nt] = (py * HXs + px + JOFF) * PITCH + lg * 8;
    }
    const int aoff = l15 * Cin_pad + lg * 8;

    f32x4 acc[MT][NT];
    #pragma unroll
    for (int i = 0; i < MT; ++i)
        #pragma unroll
        for (int j = 0; j < NT; ++j) acc[i][j] = (f32x4)0.f;

    const int c0 = blockIdx.y * cps;
    const int c1 = (c0 + cps < nchunks) ? c0 + cps : nchunks;

    for (int c = c0; c < c1; ++c) {
        const int ci0 = c * 32;
        __syncthreads();
        for (int i = tid; i < NITEM; i += 256) {
            int g  = i % G;
            int rr = (i / G) % HY;
            int cp = i / (G * HY);
            int ci = ci0 + cp * 2;
            int y  = y0 - P + rr;
            int xg = x0 - XOFF + g * 4;
            ushort* dp = &sT[(rr * HXs + g * 4) * PITCH + cp * 2];
            const float* p0 = in1 + (long long)(b * C1 + ci) * (long long)HW + (long long)y * W + xg;
            bool yok = (unsigned)y < (unsigned)H;
            #pragma unroll
            for (int u = 0; u < 4; ++u) {
                int x = xg + u;
                unsigned pk = 0;
                if (yok && (unsigned)x < (unsigned)W)
                    pk = (unsigned)f2bf(p0[u]) | ((unsigned)f2bf(p0[u + (long long)HW]) << 16);
                *(unsigned*)(dp + u * PITCH) = pk;
            }
        }
        __syncthreads();

        bf16x8 afA[MT];
        {
            const ushort* ap = wt + (size_t)co0 * Cin_pad + ci0 + aoff;
            #pragma unroll
            for (int mt = 0; mt < MT; ++mt)
                afA[mt] = *(const bf16x8*)(ap + (size_t)mt * 16 * Cin_pad);
        }
        #pragma unroll
        for (int t = 0; t < KK; ++t) {
            bf16x8 afB[MT];
            if (t + 1 < KK) {
                const ushort* ap = wt + (size_t)((t + 1) * CoutPad + co0) * Cin_pad + ci0 + aoff;
                #pragma unroll
                for (int mt = 0; mt < MT; ++mt)
                    afB[mt] = *(const bf16x8*)(ap + (size_t)mt * 16 * Cin_pad);
            }
            const int tOff = ((t / K) * HXs + (t % K)) * PITCH;
            bf16x8 bf[NT];
            #pragma unroll
            for (int nt = 0; nt < NT; ++nt)
                bf[nt] = *(const bf16x8*)(sT + posBase[nt] + tOff);
            #pragma unroll
            for (int mt = 0; mt < MT; ++mt)
                #pragma unroll
                for (int nt = 0; nt < NT; ++nt)
                    acc[mt][nt] = __builtin_amdgcn_mfma_f32_16x16x32_bf16(
                        afA[mt], bf[nt], acc[mt][nt], 0, 0, 0);
            if (t + 1 < KK) {
                #pragma unroll
                for (int mt = 0; mt < MT; ++mt) afA[mt] = afB[mt];
            }
        }
    }

    #pragma unroll
    for (int mt = 0; mt < MT; ++mt) {
        #pragma unroll
        for (int nt = 0; nt < NT; ++nt) {
            int y = y0 + py_[nt], x = x0 + px_[nt];
            if (y < H && x < W) {
                #pragma unroll
                for (int r = 0; r < 4; ++r) {
                    int co = co0 + mt * 16 + lg * 4 + r;
                    if (co < Cout) {
                        size_t o = ((size_t)(b * Cout + co)) * HW + (size_t)y * W + x;
                        unsafeAtomicAdd(&outDst[o], acc[mt][nt][r]);
                    }
                }
            }
        }
    }
}

// ---------------------------------------------------------------------------
// ConvTranspose2d k3/s2/p1/op1 via MFMA, 4-phase subpixel decomposition.
// ---------------------------------------------------------------------------
template<int TY, int TX, int NSPLIT, int MT>
__global__ __launch_bounds__(256)
void convt_mfma(const float* __restrict__ in,
                const ushort* __restrict__ wtp,
                ushort* __restrict__ out,
                int Cin, int Cout, int Cin_pad, int Hin, int Win,
                int tilesX, int tilesY) {
    constexpr int HY = TY + 1, HX = TX + 1;
    constexpr int PITCH = 40;
    constexpr int NPX = TY * TX;
    constexpr int PXW = NPX / NSPLIT;
    constexpr int NT = PXW / 16;
    constexpr int NPOS = HY * HX;
    constexpr int NIT = (NPOS * 16 + 63) & ~63;

    __shared__ ushort sT[NPOS * PITCH];

    constexpr int toy[9] = {0, 0, 0, 1, 0, 1, 1, 0, 0};
    constexpr int tox[9] = {0, 1, 0, 0, 0, 1, 0, 1, 0};
    constexpr int tph[9] = {0, 1, 1, 2, 2, 3, 3, 3, 3};

    const int tid = threadIdx.x;
    const int lane = tid & 63, wv = tid >> 6;
    const int nwave = wv % NSPLIT, mwave = wv / NSPLIT;
    const int l15 = lane & 15, lg = lane >> 4;

    int tile = blockIdx.x;
    const int txi = tile % tilesX;
    int rem = tile / tilesX;
    const int tyi = rem % tilesY;
    const int b = rem / tilesY;
    const int x0 = txi * TX, y0 = tyi * TY;
    const size_t HWi = (size_t)Hin * Win;
    const int Wo = 2 * Win;
    const size_t HWo = (size_t)4 * HWi;

    const int co0 = mwave * (MT * 16);

    int posBase[NT], py_[NT], px_[NT];
    #pragma unroll
    for (int nt = 0; nt < NT; ++nt) {
        int pidx = nwave * PXW + nt * 16 + l15;
        int py = pidx / TX, px = pidx % TX;
        py_[nt] = py; px_[nt] = px;
        posBase[nt] = (py * HX + px) * PITCH + lg * 8;
    }
    const int aoff = l15 * Cin_pad + lg * 8;

    f32x4 acc[4][MT][NT];
    #pragma unroll
    for (int p = 0; p < 4; ++p)
        #pragma unroll
        for (int i = 0; i < MT; ++i)
            #pragma unroll
            for (int j = 0; j < NT; ++j) acc[p][i][j] = (f32x4)0.f;

    const int nchunks = Cin_pad / 32;
    for (int c = 0; c < nchunks; ++c) {
        const int ci0 = c * 32;
        __syncthreads();
        for (int i = tid; i < NIT; i += 256) {
            int cp = (i >> 2) & 15;
            int pos = (i & 3) | ((i >> 6) << 2);
            if (pos < NPOS) {
                int hy = pos / HX, hx = pos % HX;
                int y = y0 + hy, x = x0 + hx;
                int ci = ci0 + cp * 2;
                unsigned pk = 0;
                if ((unsigned)y < (unsigned)Hin && (unsigned)x < (unsigned)Win && ci < Cin) {
                    const float* p0 = in + (size_t)(b * Cin + ci) * HWi + (size_t)y * Win + x;
                    float v0 = p0[0];
                    float v1 = (ci + 1 < Cin) ? p0[HWi] : 0.f;
                    pk = pack2bf(v0, v1);
                }
                *(unsigned*)&sT[pos * PITCH + cp * 2] = pk;
            }
        }
        __syncthreads();

        bf16x8 afA[MT];
        {
            const ushort* ap = wtp + (size_t)co0 * Cin_pad + ci0 + aoff;
            #pragma unroll
            for (int mt = 0; mt < MT; ++mt)
                afA[mt] = *(const bf16x8*)(ap + (size_t)mt * 16 * Cin_pad);
        }
        #pragma unroll
        for (int t = 0; t < 9; ++t) {
            bf16x8 afB[MT];
            if (t + 1 < 9) {
                const ushort* ap = wtp + (size_t)((t + 1) * Cout + co0) * Cin_pad + ci0 + aoff;
                #pragma unroll
                for (int mt = 0; mt < MT; ++mt)
                    afB[mt] = *(const bf16x8*)(ap + (size_t)mt * 16 * Cin_pad);
            }
            const int tOff = (toy[t] * HX + tox[t]) * PITCH;
            bf16x8 bf[NT];
            #pragma unroll
            for (int nt = 0; nt < NT; ++nt)
                bf[nt] = *(const bf16x8*)(sT + posBase[nt] + tOff);
            #pragma unroll
            for (int mt = 0; mt < MT; ++mt)
                #pragma unroll
                for (int nt = 0; nt < NT; ++nt)
                    acc[tph[t]][mt][nt] = __builtin_amdgcn_mfma_f32_16x16x32_bf16(
                        afA[mt], bf[nt], acc[tph[t]][mt][nt], 0, 0, 0);
            if (t + 1 < 9) {
                #pragma unroll
                for (int mt = 0; mt < MT; ++mt) afA[mt] = afB[mt];
            }
        }
    }

    #pragma unroll
    for (int dy = 0; dy < 2; ++dy) {
        #pragma unroll
        for (int mt = 0; mt < MT; ++mt) {
            #pragma unroll
            for (int nt = 0; nt < NT; ++nt) {
                int y = y0 + py_[nt], x = x0 + px_[nt];
                if (y < Hin && x < Win) {
                    #pragma unroll
                    for (int r = 0; r < 4; ++r) {
                        int co = co0 + mt * 16 + lg * 4 + r;
                        unsigned pk = pack2bf(acc[dy * 2][mt][nt][r], acc[dy * 2 + 1][mt][nt][r]);
                        *(unsigned*)&out[((size_t)(b * Cout + co)) * HWo + (size_t)(2 * y + dy) * Wo + 2 * x] = pk;
                    }
                }
            }
        }
    }
}

// ---------------------------------------------------------------------------
// InstanceNorm stats over NS fp32 partial planes.
// ---------------------------------------------------------------------------
__global__ __launch_bounds__(256)
void inorm_stats2(const float* __restrict__ x, size_t pStride, int NS,
                  float* __restrict__ mean, float* __restrict__ istd, int HW) {
    int bc = blockIdx.x;
    const float4* p = (const float4*)(x + (size_t)bc * HW);
    size_t st4 = pStride >> 2;
    int n4 = HW >> 2;
    float s = 0.f, ss = 0.f;
    for (int i = threadIdx.x; i < n4; i += 256) {
        float4 v = p[i];
        for (int sp = 1; sp < NS; ++sp) {
            float4 w = p[i + sp * st4];
            v.x += w.x; v.y += w.y; v.z += w.z; v.w += w.w;
        }
        s += v.x + v.y + v.z + v.w;
        ss += v.x * v.x + v.y * v.y + v.z * v.z + v.w * v.w;
    }
    #pragma unroll
    for (int o = 32; o > 0; o >>= 1) {
        s  += __shfl_down(s, o);
        ss += __shfl_down(ss, o);
    }
    __shared__ float sh[4][2];
    int wid = threadIdx.x >> 6, ln = threadIdx.x & 63;
    if (ln == 0) { sh[wid][0] = s; sh[wid][1] = ss; }
    __syncthreads();
    if (threadIdx.x == 0) {
        float S = 0.f, SS = 0.f;
        for (int i = 0; i < 4; ++i) { S += sh[i][0]; SS += sh[i][1]; }
        float m = S / HW;
        float v = SS / HW - m * m;
        v = v > 0.f ? v : 0.f;
        mean[bc] = m;
        istd[bc] = rsqrtf(v + 1e-5f);
    }
}

// ---------------------------------------------------------------------------
// Epilogue over fp32 partial planes: feat = relu((Σraw - m)*istd) [+ Σres + br]
// RESMODE: 0 none, 1 fp32 res planes, 2 bf16 res single plane.
// ---------------------------------------------------------------------------
template<int RESMODE>
__global__ __launch_bounds__(256)
void epilogue2(const float* __restrict__ raw, size_t rawStride, int NS,
               const float* __restrict__ mean,
               const float* __restrict__ istd,
               const void* __restrict__ res, size_t resStride, int NSR,
               const float* __restrict__ br,
               float* __restrict__ feat,
               int HW, int Cout, int total4) {
    int i = blockIdx.x * 256 + threadIdx.x;
    if (i >= total4) return;
    int bc = (int)(((long long)i * 4) / HW);
    float m = mean[bc], is = istd[bc];
    size_t rs4 = rawStride >> 2;
    float4 r = ((const float4*)raw)[i];
    for (int sp = 1; sp < NS; ++sp) {
        float4 w = ((const float4*)raw)[i + sp * rs4];
        r.x += w.x; r.y += w.y; r.z += w.z; r.w += w.w;
    }
    float4 o;
    o.x = fmaxf((r.x - m) * is, 0.f);
    o.y = fmaxf((r.y - m) * is, 0.f);
    o.z = fmaxf((r.z - m) * is, 0.f);
    o.w = fmaxf((r.w - m) * is, 0.f);
    if (RESMODE == 1) {
        float bb = br[bc % Cout];
        size_t es4 = resStride >> 2;
        float4 e = ((const float4*)res)[i];
        for (int sp = 1; sp < NSR; ++sp) {
            float4 w = ((const float4*)res)[i + sp * es4];
            e.x += w.x; e.y += w.y; e.z += w.z; e.w += w.w;
        }
        o.x += e.x + bb; o.y += e.y + bb; o.z += e.z + bb; o.w += e.w + bb;
    } else if (RESMODE == 2) {
        float bb = br[bc % Cout];
        ushort4 e = ((const ushort4*)res)[i];
        o.x += bf2f(e.x) + bb; o.y += bf2f(e.y) + bb;
        o.z += bf2f(e.z) + bb; o.w += bf2f(e.w) + bb;
    }
    ((float4*)feat)[i] = o;
}

extern "C" void kernel_launch(void* const* d_in, const int* in_sizes, int n_in,
                              void* d_out, int out_size, void* d_ws, size_t ws_size,
                              hipStream_t stream) {
    const float* f4   = (const float*)d_in[0];
    const float* f8   = (const float*)d_in[1];
    const float* f16  = (const float*)d_in[2];
    const float* f32  = (const float*)d_in[3];
    const float* w32  = (const float*)d_in[4];
    const float* wt32 = (const float*)d_in[6];
    const float* w16  = (const float*)d_in[7];
    const float* wr16 = (const float*)d_in[9];
    const float* br16 = (const float*)d_in[10];
    const float* wt16 = (const float*)d_in[11];
    const float* w8   = (const float*)d_in[12];
    const float* wr8  = (const float*)d_in[14];
    const float* br8  = (const float*)d_in[15];
    const float* wt8  = (const float*)d_in[16];
    const float* w4   = (const float*)d_in[17];
    const float* wr4  = (const float*)d_in[19];
    const float* br4  = (const float*)d_in[20];
    // main-conv biases cancel under InstanceNorm -> unused.

    float* out = (float*)d_out;

    const int B = 2, C = 256;
    const int H4 = 160, W4 = 240;
    const int H8 = 80,  W8 = 120;
    const int H16 = 40, W16 = 60;
    const int H32 = 20, W32 = 30;

    float* feat4  = out;
    float* feat8  = out + (size_t)B * 48 * H4 * W4;
    float* feat16 = feat8 + (size_t)B * 64 * H8 * W8;
    float* feat32 = feat16 + (size_t)B * 192 * H16 * W16;

    const size_t bufElems = (size_t)B * 48 * H4 * W4;  // 3,686,400
    ushort* wsUpB  = (ushort*)d_ws;
    float*  wsRawP = (float*)(wsUpB + bufElems);
    ushort* wsResB = (ushort*)(wsRawP + bufElems);
    float*  stMean = (float*)(wsResB + bufElems);
    float*  stIstd = stMean + 512;
    float*  wsResF = (float*)wsResB;

    // bf16 repacked weights in the feat4 output region (written last).
    ushort* wb = (ushort*)feat4;
    ushort* W32p = wb;                          // 9*192*256
    ushort* W16p = W32p + 9 * 192 * 256;        // 25*192*448
    ushort* W8p  = W16p + 25 * 192 * 448;       // 25*64*320
    ushort* W4p  = W8p  + 25 * 64 * 320;        // 25*64*320 (Cout pad 48->64)
    ushort* R16p = W4p  + 25 * 64 * 320;        // 192*256
    ushort* R8p  = R16p + 192 * 256;            // 64*256
    ushort* R4p  = R8p  + 64 * 256;             // 64*256 (pad)
    ushort* T32p = R4p  + 64 * 256;             // 9*192*160
    ushort* T16p = T32p + 9 * 192 * 160;        // 9*64*192
    ushort* T8p  = T16p + 9 * 64 * 192;         // 9*48*64

    // ---- weight repacks ----
    {
        int t1 = 9 * 192 * 256;
        transpose_w<<<cdiv(t1, 256), 256, 0, stream>>>(w32, W32p, 160, 192, 256, 256, 9, t1);
        int t2 = 25 * 192 * 448;
        transpose_w<<<cdiv(t2, 256), 256, 0, stream>>>(w16, W16p, 192, 192, 448, 448, 25, t2);
        int t3 = 25 * 64 * 320;
        transpose_w<<<cdiv(t3, 256), 256, 0, stream>>>(w8, W8p, 64, 64, 320, 320, 25, t3);
        int t4 = 25 * 64 * 320;
        transpose_w<<<cdiv(t4, 256), 256, 0, stream>>>(w4, W4p, 48, 64, 304, 320, 25, t4);
        int t5 = 192 * 256;
        transpose_w<<<cdiv(t5, 256), 256, 0, stream>>>(wr16, R16p, 192, 192, 256, 256, 1, t5);
        int t6 = 64 * 256;
        transpose_w<<<cdiv(t6, 256), 256, 0, stream>>>(wr8, R8p, 64, 64, 256, 256, 1, t6);
        int t7 = 64 * 256;
        transpose_w<<<cdiv(t7, 256), 256, 0, stream>>>(wr4, R4p, 48, 64, 256, 256, 1, t7);
        int u1 = 9 * 192 * 160;
        transpose_wt<<<cdiv(u1, 256), 256, 0, stream>>>(wt32, T32p, 160, 192, 160, u1);
        int u2 = 9 * 64 * 192;
        transpose_wt<<<cdiv(u2, 256), 256, 0, stream>>>(wt16, T16p, 192, 64, 192, u2);
        int u3 = 9 * 48 * 64;
        transpose_wt<<<cdiv(u3, 256), 256, 0, stream>>>(wt8, T8p, 64, 48, 64, u3);
    }

    // ---------------- stage 32 (K=3, Cin=256, Cout=160, 20x30) ----------------
    {
        hipMemsetAsync(wsRawP, 0, (size_t)B * 160 * H32 * W32 * 4, stream);
        int tX = cdiv(W32, 8), tY = cdiv(H32, 4);   // 4 x 5
        dim3 g(tX * tY, 8, B);
        conv_mfma5<3, 4, 8, 1, 4, 3><<<g, 256, 0, stream>>>(
            f32, C, C, W32p, wsRawP, H32, W32, 160, 192, 256, tX, 8, 1);
        inorm_stats2<<<B * 160, 256, 0, stream>>>(wsRawP, 0, 1, stMean, stIstd, H32 * W32);
        int tot4 = B * 160 * H32 * W32 / 4;
        epilogue2<0><<<cdiv(tot4, 256), 256, 0, stream>>>(
            wsRawP, 0, 1, stMean, stIstd, nullptr, 0, 0, nullptr, feat32, H32 * W32, 160, tot4);
        int uX = cdiv(W32, 8), uY = cdiv(H32, 2);
        convt_mfma<2, 8, 1, 3><<<uX * uY * B, 256, 0, stream>>>(
            feat32, T32p, wsUpB, 160, 192, 160, H32, W32, uX, uY);
    }
    // ---------------- stage 16 (K=5, Cin=256+192, Cout=192, 40x60) ------------
    {
        size_t SZ16 = (size_t)B * 192 * H16 * W16;  // 921,600
        int tX = cdiv(W16, 8), tY = cdiv(H16, 4);   // 8 x 10 = 80 tiles
        dim3 g(tX * tY, 6, B);                       // y 0-3 main, 4-5 res (chunk64)
        conv_dual<4, 8, 1, 4, 3, 5, 0, 1, 0, true><<<g, 256, 0, stream>>>(
            f16, C, wsUpB, 192, 448,
            W16p, wsRawP, SZ16, 192, 448, 7, 2, 4,
            R16p, wsResF, SZ16, 192, 256, 4, 2,
            H16, W16, 192, tX, tY);
        inorm_stats2<<<B * 192, 256, 0, stream>>>(wsRawP, SZ16, 4, stMean, stIstd, H16 * W16);
        int tot4 = (int)(SZ16 / 4);
        epilogue2<1><<<cdiv(tot4, 256), 256, 0, stream>>>(
            wsRawP, SZ16, 4, stMean, stIstd, wsResF, SZ16, 2, br16, feat16, H16 * W16, 192, tot4);
        int uX = cdiv(W16, 8), uY = cdiv(H16, 4);
        convt_mfma<4, 8, 2, 2><<<uX * uY * B, 256, 0, stream>>>(
            feat16, T16p, wsUpB, 192, 64, 192, H16, W16, uX, uY);
    }
    // ---------------- stage 8 (K=5, Cin=256+64, Cout=64, 80x120) --------------
    {
        size_t SZ8 = (size_t)B * 64 * H8 * W8;      // 1,228,800
        int tX = cdiv(W8, 16), tY = cdiv(H8, 8);    // 8 x 10 = 80 tiles
        dim3 g(tX * tY, 4, B);                       // y 0-2 main, 3 res (chunk64)
        conv_dual<8, 16, 2, 2, 2, 5, 0, 1, 0, true><<<g, 256, 0, stream>>>(
            f8, C, wsUpB, 64, 320,
            W8p, wsRawP, SZ8, 64, 320, 5, 2, 3,
            R8p, wsResF, SZ8, 64, 256, 4, 4,
            H8, W8, 64, tX, tY);
        inorm_stats2<<<B * 64, 256, 0, stream>>>(wsRawP, SZ8, 3, stMean, stIstd, H8 * W8);
        int tot4 = (int)(SZ8 / 4);
        epilogue2<1><<<cdiv(tot4, 256), 256, 0, stream>>>(
            wsRawP, SZ8, 3, stMean, stIstd, wsResF, SZ8, 1, br8, feat8, H8 * W8, 64, tot4);
        int uX = cdiv(W8, 16), uY = cdiv(H8, 4);
        convt_mfma<4, 16, 4, 3><<<uX * uY * B, 256, 0, stream>>>(
            feat8, T8p, wsUpB, 64, 48, 64, H8, W8, uX, uY);
    }
    // ---------------- stage 4 (K=5, Cin=256+48, Cout=48->64pad, 160x240) ------
    {
        size_t SZ4 = (size_t)B * 48 * H4 * W4;      // 3,686,400
        int tX = cdiv(W4, 16), tY = cdiv(H4, 8);    // 15 x 20 = 300 tiles
        dim3 g(tX * tY, 2, B);                       // y 0 main, 1 res (chunk32:
                                                     // LDS 23KB -> 6 blk/CU cap,
                                                     // grid 4.7/CU now resident)
        conv_dual<8, 16, 2, 2, 2, 5, 0, 1, 2, false><<<g, 256, 0, stream>>>(
            f4, C, wsUpB, 48, 304,
            W4p, wsRawP, SZ4, 64, 320, 10, 10, 1,
            R4p, wsResB, 0, 64, 256, 8, 8,
            H4, W4, 48, tX, tY);
        inorm_stats2<<<B * 48, 256, 0, stream>>>(wsRawP, 0, 1, stMean, stIstd, H4 * W4);
        int tot4 = (int)(SZ4 / 4);
        epilogue2<2><<<cdiv(tot4, 256), 256, 0, stream>>>(
            wsRawP, 0, 1, stMean, stIstd, wsResB, 0, 0, br4, feat4, H4 * W4, 48, tot4);
    }
}